// Round 1
// baseline (1501.318 us; speedup 1.0000x reference)
//
#include <hip/hip_runtime.h>
#include <hip/hip_bf16.h>
#include <math.h>

#define Bb   8
#define Qq   300
#define Cc   256
#define NHh  8
#define DHh  32
#define Ss   21760
#define DFFf 1024
#define LN_EPS 1e-5f

typedef __hip_bfloat16 bf16;

template<typename T> __device__ inline T cvt_out(float v);
template<> __device__ inline float cvt_out<float>(float v){ return v; }
template<> __device__ inline bf16  cvt_out<bf16>(float v){ return __float2bfloat16(v); }

// ---------------------------------------------------------------------------
// Generic tiled fp32 GEMM: C[M,N] = act((A (+A2)) @ W^T + bias)
// W is [N,K] row-major (PyTorch-style). 64x64 tile, BK=16, 4x4 per thread.
// ---------------------------------------------------------------------------
template<bool RELU, typename OutT>
__global__ __launch_bounds__(256) void gemm_tiled(
    const float* __restrict__ A, const float* __restrict__ A2,
    const float* __restrict__ W, const float* __restrict__ bias,
    OutT* __restrict__ C, int M, int N, int K)
{
  __shared__ float As[16][65];
  __shared__ float Ws[16][65];
  const int tid = threadIdx.x;
  const int m0 = blockIdx.y * 64;
  const int n0 = blockIdx.x * 64;
  const int lr = tid >> 2;          // 0..63 row within tile (load)
  const int lc = (tid & 3) * 4;     // 0,4,8,12 k-offset (load)
  const int tr = (tid >> 4) * 4;    // compute rows
  const int tc = (tid & 15) * 4;    // compute cols
  float acc[4][4] = {};
  const int nkt = K >> 4;
  for (int kt = 0; kt < nkt; ++kt) {
    const int k = kt * 16 + lc;
    float4 av;
    const int ar = m0 + lr;
    if (ar < M) {
      av = *reinterpret_cast<const float4*>(A + (size_t)ar * K + k);
      if (A2) {
        float4 a2 = *reinterpret_cast<const float4*>(A2 + (size_t)ar * K + k);
        av.x += a2.x; av.y += a2.y; av.z += a2.z; av.w += a2.w;
      }
    } else {
      av = make_float4(0.f, 0.f, 0.f, 0.f);
    }
    float4 wv = *reinterpret_cast<const float4*>(W + (size_t)(n0 + lr) * K + k);
    As[lc+0][lr] = av.x; As[lc+1][lr] = av.y; As[lc+2][lr] = av.z; As[lc+3][lr] = av.w;
    Ws[lc+0][lr] = wv.x; Ws[lc+1][lr] = wv.y; Ws[lc+2][lr] = wv.z; Ws[lc+3][lr] = wv.w;
    __syncthreads();
    #pragma unroll
    for (int kk = 0; kk < 16; ++kk) {
      float a[4], w[4];
      #pragma unroll
      for (int i = 0; i < 4; ++i) a[i] = As[kk][tr + i];
      #pragma unroll
      for (int j = 0; j < 4; ++j) w[j] = Ws[kk][tc + j];
      #pragma unroll
      for (int i = 0; i < 4; ++i)
        #pragma unroll
        for (int j = 0; j < 4; ++j)
          acc[i][j] = fmaf(a[i], w[j], acc[i][j]);
    }
    __syncthreads();
  }
  #pragma unroll
  for (int i = 0; i < 4; ++i) {
    const int m = m0 + tr + i;
    if (m < M) {
      #pragma unroll
      for (int j = 0; j < 4; ++j) {
        float v = acc[i][j] + bias[n0 + tc + j];
        if (RELU) v = fmaxf(v, 0.f);
        C[(size_t)m * N + n0 + tc + j] = cvt_out<OutT>(v);
      }
    }
  }
}

// ---------------------------------------------------------------------------
// Self-attention: one wave per (b,h,q) row. Q=300 keys, DH=32.
// ---------------------------------------------------------------------------
__global__ __launch_bounds__(256) void attn_kernel(
    const float* __restrict__ qh, const float* __restrict__ kh,
    const float* __restrict__ vh, float* __restrict__ sa)
{
  const int gw = (int)((blockIdx.x * (size_t)blockDim.x + threadIdx.x) >> 6);
  const int lane = threadIdx.x & 63;
  if (gw >= Bb * NHh * Qq) return;
  const int qi = gw % Qq;
  const int bh = gw / Qq;
  const int h = bh % NHh;
  const int b = bh / NHh;
  const float scale = 0.17677669529663687f;  // 1/sqrt(32)
  const float* qv = qh + (size_t)(b * Qq + qi) * Cc + h * DHh;
  float e[5];
  float mx = -1e30f;
  #pragma unroll
  for (int i = 0; i < 5; ++i) {
    const int k = lane + i * 64;
    const int kc = (k < Qq) ? k : (Qq - 1);
    const float* kv = kh + (size_t)(b * Qq + kc) * Cc + h * DHh;
    float s = 0.f;
    #pragma unroll
    for (int d = 0; d < DHh; ++d) s = fmaf(qv[d], kv[d], s);
    e[i] = (k < Qq) ? s * scale : -1e30f;
    mx = fmaxf(mx, e[i]);
  }
  #pragma unroll
  for (int o = 32; o; o >>= 1) mx = fmaxf(mx, __shfl_xor(mx, o));
  float ssum = 0.f;
  #pragma unroll
  for (int i = 0; i < 5; ++i) { e[i] = expf(e[i] - mx); ssum += e[i]; }
  #pragma unroll
  for (int o = 32; o; o >>= 1) ssum += __shfl_xor(ssum, o);
  const float inv = 1.f / ssum;
  float* so = sa + (size_t)(b * Qq + qi) * Cc + h * DHh;
  for (int d = 0; d < DHh; ++d) {
    float p = 0.f;
    #pragma unroll
    for (int i = 0; i < 5; ++i) {
      const int k = lane + i * 64;
      const int kc = (k < Qq) ? k : (Qq - 1);
      p = fmaf(e[i], vh[(size_t)(b * Qq + kc) * Cc + h * DHh + d], p);
    }
    #pragma unroll
    for (int o = 32; o; o >>= 1) p += __shfl_xor(p, o);
    if (lane == 0) so[d] = p * inv;
  }
}

// ---------------------------------------------------------------------------
// Fused residual-add + LayerNorm over C=256. One block (256 thr) per row.
// ---------------------------------------------------------------------------
__global__ __launch_bounds__(256) void ln_kernel(
    const float* __restrict__ x, const float* __restrict__ y,
    const float* __restrict__ g, const float* __restrict__ bta,
    float* __restrict__ out)
{
  const int row = blockIdx.x;
  const int t = threadIdx.x;
  const size_t idx = (size_t)row * Cc + t;
  const float v = x[idx] + y[idx];
  float s = v;
  #pragma unroll
  for (int o = 32; o; o >>= 1) s += __shfl_xor(s, o);
  __shared__ float ps[4], qs[4];
  const int wid = t >> 6, lane = t & 63;
  if (lane == 0) ps[wid] = s;
  __syncthreads();
  const float mean = (ps[0] + ps[1] + ps[2] + ps[3]) * (1.f / Cc);
  const float dv = v - mean;
  float s2 = dv * dv;
  #pragma unroll
  for (int o = 32; o; o >>= 1) s2 += __shfl_xor(s2, o);
  if (lane == 0) qs[wid] = s2;
  __syncthreads();
  const float var = (qs[0] + qs[1] + qs[2] + qs[3]) * (1.f / Cc);
  out[idx] = dv * rsqrtf(var + LN_EPS) * g[t] + bta[t];
}

// ---------------------------------------------------------------------------
// Deformable sampling: one wave per (b,q,h). lane = 32*half + d.
// half handles points p = {0,2} vs {1,3} of each level; reduce across halves.
// ---------------------------------------------------------------------------
__global__ __launch_bounds__(256) void deform_kernel(
    const float* __restrict__ offb, const float* __restrict__ awl,
    const float* __restrict__ refp, const bf16* __restrict__ value,
    float* __restrict__ accp)
{
  const int gw = (int)((blockIdx.x * (size_t)blockDim.x + threadIdx.x) >> 6);
  if (gw >= Bb * Qq * NHh) return;
  const int lane = threadIdx.x & 63;
  const int h = gw % NHh;
  const int t = gw / NHh;
  const int qi = t % Qq;
  const int b = t / Qq;
  const int half = lane >> 5;
  const int d = lane & 31;

  // softmax over the 16 attention logits (redundant per lane)
  const float* awp = awl + (size_t)(b * Qq + qi) * 128 + h * 16;
  float e[16];
  float mx = -1e30f;
  #pragma unroll
  for (int i = 0; i < 16; ++i) { e[i] = awp[i]; mx = fmaxf(mx, e[i]); }
  float s = 0.f;
  #pragma unroll
  for (int i = 0; i < 16; ++i) { e[i] = expf(e[i] - mx); s += e[i]; }
  const float inv = 1.f / s;

  const float* offp = offb + (size_t)(b * Qq + qi) * Cc + h * 32;
  const float* rp = refp + (size_t)(b * Qq + qi) * 8;
  const int lH[4] = {128, 64, 32, 16};
  const int lW[4] = {128, 64, 32, 16};
  const int lS[4] = {0, 16384, 20480, 21504};

  float acc = 0.f;
  #pragma unroll
  for (int l = 0; l < 4; ++l) {
    const int Hl = lH[l], Wl = lW[l], st = lS[l];
    const float rx = rp[l * 2 + 0], ry = rp[l * 2 + 1];
    #pragma unroll
    for (int pp = 0; pp < 2; ++pp) {
      const int p = pp * 2 + half;
      const float ax = offp[l * 8 + p * 2 + 0];
      const float ay = offp[l * 8 + p * 2 + 1];
      const float x = (rx + ax / (float)Wl) * (float)Wl - 0.5f;
      const float y = (ry + ay / (float)Hl) * (float)Hl - 0.5f;
      const float x0f = floorf(x), y0f = floorf(y);
      const float wx = x - x0f, wy = y - y0f;
      const int x0 = (int)x0f, y0 = (int)y0f;
      const float wp = e[l * 4 + p] * inv;
      #pragma unroll
      for (int dy = 0; dy < 2; ++dy) {
        #pragma unroll
        for (int dx = 0; dx < 2; ++dx) {
          const int xi = x0 + dx, yi = y0 + dy;
          if (xi >= 0 && xi < Wl && yi >= 0 && yi < Hl) {
            const float w = (dx ? wx : 1.f - wx) * (dy ? wy : 1.f - wy);
            const bf16* vrow = value + ((size_t)(b * (size_t)Ss + st + yi * Wl + xi) * Cc + h * 32);
            acc = fmaf(wp * w, __bfloat162float(vrow[d]), acc);
          }
        }
      }
    }
  }
  acc += __shfl_xor(acc, 32);
  if (lane < 32) accp[(size_t)(b * Qq + qi) * Cc + h * 32 + d] = acc;
}

// ---------------------------------------------------------------------------
extern "C" void kernel_launch(void* const* d_in, const int* in_sizes, int n_in,
                              void* d_out, int out_size, void* d_ws, size_t ws_size,
                              hipStream_t stream) {
  const float* tgt   = (const float*)d_in[0];
  // d_in[1] = tgt_box (unused by reference)
  const float* qpos  = (const float*)d_in[2];
  const float* refp  = (const float*)d_in[3];
  const float* src   = (const float*)d_in[4];
  // d_in[5] spatial_shapes, d_in[6] level_start_index (compile-time constants)
  // d_in[7] src_padding_mask (all False in setup)
  const float* wq = (const float*)d_in[8];   const float* bq = (const float*)d_in[9];
  const float* wk = (const float*)d_in[10];  const float* bk = (const float*)d_in[11];
  const float* wv = (const float*)d_in[12];  const float* bv = (const float*)d_in[13];
  const float* wo = (const float*)d_in[14];  const float* bo = (const float*)d_in[15];
  const float* w_off = (const float*)d_in[16];  const float* b_off = (const float*)d_in[17];
  const float* w_attn = (const float*)d_in[18]; const float* b_attn = (const float*)d_in[19];
  const float* w_val = (const float*)d_in[20];  const float* b_val = (const float*)d_in[21];
  const float* w_out = (const float*)d_in[22];  const float* b_out = (const float*)d_in[23];
  const float* w1 = (const float*)d_in[24];  const float* b1 = (const float*)d_in[25];
  const float* w2 = (const float*)d_in[26];  const float* b2 = (const float*)d_in[27];
  const float* ln2g = (const float*)d_in[28]; const float* ln2b = (const float*)d_in[29];
  const float* ln1g = (const float*)d_in[30]; const float* ln1b = (const float*)d_in[31];
  const float* ln3g = (const float*)d_in[32]; const float* ln3b = (const float*)d_in[33];

  float* fws = (float*)d_ws;
  const size_t NBQ = (size_t)Bb * Qq * Cc;  // 614400
  float* qhb  = fws;
  float* khb  = qhb  + NBQ;
  float* vhb  = khb  + NBQ;
  float* sab  = vhb  + NBQ;
  float* sapb = sab  + NBQ;
  float* tgt1 = sapb + NBQ;
  float* offb = tgt1 + NBQ;
  float* awlb = offb + NBQ;   // only 2400*128 used
  float* accb = awlb + NBQ;
  float* t2pb = accb + NBQ;
  float* t2nb = t2pb + NBQ;
  float* ffhb = t2nb + NBQ;   // 2400*1024
  float* ff2b = ffhb + (size_t)Bb * Qq * DFFf;
  bf16*  valb = (bf16*)(ff2b + NBQ);  // 174080*256 bf16

  const int MQ = Bb * Qq;  // 2400
  dim3 blk(256, 1, 1);
  dim3 gProj(Cc / 64, (MQ + 63) / 64);

  // self-attention projections (q = tgt + query_pos fused into GEMM A-load)
  gemm_tiled<false, float><<<gProj, blk, 0, stream>>>(tgt, qpos, wq, bq, qhb, MQ, Cc, Cc);
  gemm_tiled<false, float><<<gProj, blk, 0, stream>>>(tgt, qpos, wk, bk, khb, MQ, Cc, Cc);
  gemm_tiled<false, float><<<gProj, blk, 0, stream>>>(tgt, nullptr, wv, bv, vhb, MQ, Cc, Cc);
  attn_kernel<<<dim3(Bb * NHh * Qq / 4), blk, 0, stream>>>(qhb, khb, vhb, sab);
  gemm_tiled<false, float><<<gProj, blk, 0, stream>>>(sab, nullptr, wo, bo, sapb, MQ, Cc, Cc);
  ln_kernel<<<dim3(MQ), blk, 0, stream>>>(tgt, sapb, ln2g, ln2b, tgt1);

  // value projection (dominant GEMM) -> bf16
  gemm_tiled<false, bf16><<<dim3(Cc / 64, (Bb * Ss) / 64), blk, 0, stream>>>(
      src, nullptr, w_val, b_val, valb, Bb * Ss, Cc, Cc);

  // offsets + attention-weight logits (query = tgt1 + query_pos fused)
  gemm_tiled<false, float><<<gProj, blk, 0, stream>>>(tgt1, qpos, w_off, b_off, offb, MQ, Cc, Cc);
  gemm_tiled<false, float><<<dim3(128 / 64, (MQ + 63) / 64), blk, 0, stream>>>(
      tgt1, qpos, w_attn, b_attn, awlb, MQ, 128, Cc);

  deform_kernel<<<dim3(Bb * Qq * NHh / 4), blk, 0, stream>>>(offb, awlb, refp, valb, accb);

  gemm_tiled<false, float><<<gProj, blk, 0, stream>>>(accb, nullptr, w_out, b_out, t2pb, MQ, Cc, Cc);
  ln_kernel<<<dim3(MQ), blk, 0, stream>>>(tgt1, t2pb, ln1g, ln1b, t2nb);

  // FFN
  gemm_tiled<true, float><<<dim3(DFFf / 64, (MQ + 63) / 64), blk, 0, stream>>>(
      t2nb, nullptr, w1, b1, ffhb, MQ, DFFf, Cc);
  gemm_tiled<false, float><<<gProj, blk, 0, stream>>>(ffhb, nullptr, w2, b2, ff2b, MQ, Cc, DFFf);
  ln_kernel<<<dim3(MQ), blk, 0, stream>>>(t2nb, ff2b, ln3g, ln3b, (float*)d_out);
}

// Round 2
// 516.512 us; speedup vs baseline: 2.9066x; 2.9066x over previous
//
#include <hip/hip_runtime.h>
#include <hip/hip_bf16.h>
#include <math.h>

#define Bb   8
#define Qq   300
#define Cc   256
#define NHh  8
#define DHh  32
#define Ss   21760
#define DFFf 1024
#define LN_EPS 1e-5f

typedef __hip_bfloat16 bf16;
typedef unsigned short u16;
typedef __bf16 bf16x8_t __attribute__((ext_vector_type(8)));
typedef float f32x4_t __attribute__((ext_vector_type(4)));
typedef u16 u16x8_t __attribute__((ext_vector_type(8)));

__device__ inline u16 f2bf(float f) {
  union { float f; unsigned int u; } v; v.f = f;
  unsigned int u = v.u + 0x7fffu + ((v.u >> 16) & 1u);
  return (u16)(u >> 16);
}
__device__ inline float bf2f(u16 s) {
  union { unsigned int u; float f; } v; v.u = ((unsigned int)s) << 16;
  return v.f;
}

template<typename T> __device__ inline T cvt_out(float v);
template<> __device__ inline float cvt_out<float>(float v){ return v; }
template<> __device__ inline bf16  cvt_out<bf16>(float v){ return __float2bfloat16(v); }

// ---------------------------------------------------------------------------
// Generic tiled fp32 GEMM: C[M,N] = act((A (+A2)) @ W^T + bias)
// ---------------------------------------------------------------------------
template<bool RELU, typename OutT>
__global__ __launch_bounds__(256) void gemm_tiled(
    const float* __restrict__ A, const float* __restrict__ A2,
    const float* __restrict__ W, const float* __restrict__ bias,
    OutT* __restrict__ C, int M, int N, int K)
{
  __shared__ float As[16][65];
  __shared__ float Ws[16][65];
  const int tid = threadIdx.x;
  const int m0 = blockIdx.y * 64;
  const int n0 = blockIdx.x * 64;
  const int lr = tid >> 2;
  const int lc = (tid & 3) * 4;
  const int tr = (tid >> 4) * 4;
  const int tc = (tid & 15) * 4;
  float acc[4][4] = {};
  const int nkt = K >> 4;
  for (int kt = 0; kt < nkt; ++kt) {
    const int k = kt * 16 + lc;
    float4 av;
    const int ar = m0 + lr;
    if (ar < M) {
      av = *reinterpret_cast<const float4*>(A + (size_t)ar * K + k);
      if (A2) {
        float4 a2 = *reinterpret_cast<const float4*>(A2 + (size_t)ar * K + k);
        av.x += a2.x; av.y += a2.y; av.z += a2.z; av.w += a2.w;
      }
    } else {
      av = make_float4(0.f, 0.f, 0.f, 0.f);
    }
    float4 wv = *reinterpret_cast<const float4*>(W + (size_t)(n0 + lr) * K + k);
    As[lc+0][lr] = av.x; As[lc+1][lr] = av.y; As[lc+2][lr] = av.z; As[lc+3][lr] = av.w;
    Ws[lc+0][lr] = wv.x; Ws[lc+1][lr] = wv.y; Ws[lc+2][lr] = wv.z; Ws[lc+3][lr] = wv.w;
    __syncthreads();
    #pragma unroll
    for (int kk = 0; kk < 16; ++kk) {
      float a[4], w[4];
      #pragma unroll
      for (int i = 0; i < 4; ++i) a[i] = As[kk][tr + i];
      #pragma unroll
      for (int j = 0; j < 4; ++j) w[j] = Ws[kk][tc + j];
      #pragma unroll
      for (int i = 0; i < 4; ++i)
        #pragma unroll
        for (int j = 0; j < 4; ++j)
          acc[i][j] = fmaf(a[i], w[j], acc[i][j]);
    }
    __syncthreads();
  }
  #pragma unroll
  for (int i = 0; i < 4; ++i) {
    const int m = m0 + tr + i;
    if (m < M) {
      #pragma unroll
      for (int j = 0; j < 4; ++j) {
        float v = acc[i][j] + bias[n0 + tc + j];
        if (RELU) v = fmaxf(v, 0.f);
        C[(size_t)m * N + n0 + tc + j] = cvt_out<OutT>(v);
      }
    }
  }
}

// ---------------------------------------------------------------------------
// Value projection with MFMA: out[M,256](bf16) = src[M,256] @ w_val[256,256]^T + b
// 128x128 tile, BK=32, 4 waves, each wave 64x64 via 4x4 mfma_16x16x32_bf16.
// fp32 inputs converted to bf16 during reg-staging into padded LDS.
// ---------------------------------------------------------------------------
__global__ __launch_bounds__(256) void value_gemm_mfma(
    const float* __restrict__ A, const float* __restrict__ Wt,
    const float* __restrict__ bias, bf16* __restrict__ out)
{
  __shared__ u16 As[128][40];
  __shared__ u16 Bs[128][40];
  const int tid = threadIdx.x;
  const int m0 = blockIdx.y * 128;
  const int n0 = blockIdx.x * 128;
  const int w = tid >> 6, lane = tid & 63;
  const int wm = w >> 1, wn = w & 1;
  const int fr = lane & 15, fq = lane >> 4;
  const int sr = tid >> 1;            // staging row 0..127
  const int sk = (tid & 1) * 16;      // staging k offset {0,16}

  f32x4_t acc[4][4];
  const f32x4_t zz = {0.f, 0.f, 0.f, 0.f};
  #pragma unroll
  for (int m = 0; m < 4; ++m)
    #pragma unroll
    for (int n = 0; n < 4; ++n) acc[m][n] = zz;

  for (int kt = 0; kt < 8; ++kt) {
    const int kg = kt * 32 + sk;
    const float4* ap = reinterpret_cast<const float4*>(A + (size_t)(m0 + sr) * 256 + kg);
    const float4* bp = reinterpret_cast<const float4*>(Wt + (size_t)(n0 + sr) * 256 + kg);
    const float4 a0 = ap[0], a1 = ap[1], a2 = ap[2], a3 = ap[3];
    const float4 b0 = bp[0], b1 = bp[1], b2 = bp[2], b3 = bp[3];
    const u16x8_t pa0 = { f2bf(a0.x), f2bf(a0.y), f2bf(a0.z), f2bf(a0.w),
                          f2bf(a1.x), f2bf(a1.y), f2bf(a1.z), f2bf(a1.w) };
    const u16x8_t pa1 = { f2bf(a2.x), f2bf(a2.y), f2bf(a2.z), f2bf(a2.w),
                          f2bf(a3.x), f2bf(a3.y), f2bf(a3.z), f2bf(a3.w) };
    const u16x8_t pb0 = { f2bf(b0.x), f2bf(b0.y), f2bf(b0.z), f2bf(b0.w),
                          f2bf(b1.x), f2bf(b1.y), f2bf(b1.z), f2bf(b1.w) };
    const u16x8_t pb1 = { f2bf(b2.x), f2bf(b2.y), f2bf(b2.z), f2bf(b2.w),
                          f2bf(b3.x), f2bf(b3.y), f2bf(b3.z), f2bf(b3.w) };
    __syncthreads();     // previous iteration's reads complete
    *reinterpret_cast<u16x8_t*>(&As[sr][sk])     = pa0;
    *reinterpret_cast<u16x8_t*>(&As[sr][sk + 8]) = pa1;
    *reinterpret_cast<u16x8_t*>(&Bs[sr][sk])     = pb0;
    *reinterpret_cast<u16x8_t*>(&Bs[sr][sk + 8]) = pb1;
    __syncthreads();
    bf16x8_t af[4], bfr[4];
    #pragma unroll
    for (int m = 0; m < 4; ++m)
      af[m] = *reinterpret_cast<const bf16x8_t*>(&As[wm*64 + m*16 + fr][fq*8]);
    #pragma unroll
    for (int n = 0; n < 4; ++n)
      bfr[n] = *reinterpret_cast<const bf16x8_t*>(&Bs[wn*64 + n*16 + fr][fq*8]);
    #pragma unroll
    for (int m = 0; m < 4; ++m)
      #pragma unroll
      for (int n = 0; n < 4; ++n)
        acc[m][n] = __builtin_amdgcn_mfma_f32_16x16x32_bf16(af[m], bfr[n], acc[m][n], 0, 0, 0);
  }

  #pragma unroll
  for (int m = 0; m < 4; ++m) {
    const int row = m0 + wm*64 + m*16 + fq*4;
    #pragma unroll
    for (int n = 0; n < 4; ++n) {
      const int col = n0 + wn*64 + n*16 + fr;
      const float bc = bias[col];
      #pragma unroll
      for (int j = 0; j < 4; ++j)
        out[(size_t)(row + j) * 256 + col] = __float2bfloat16(acc[m][n][j] + bc);
    }
  }
}

// ---------------------------------------------------------------------------
// Self-attention v2: block per (b,h,q-half). K (pre-scaled fp32) + V (bf16)
// staged in LDS; thread-per-row two-pass softmax; all LDS reads broadcast.
// ---------------------------------------------------------------------------
__global__ __launch_bounds__(256) void attn2_kernel(
    const float* __restrict__ qh, const float* __restrict__ kh,
    const float* __restrict__ vh, float* __restrict__ sa)
{
  __shared__ float Kf[300][32];
  __shared__ u16  Vb[300][32];
  const int bh = blockIdx.x >> 1;
  const int halfq = blockIdx.x & 1;
  const int h = bh & 7, b = bh >> 3;
  const int tid = threadIdx.x;
  const size_t base = ((size_t)b * Qq) * Cc + h * DHh;
  for (int idx = tid; idx < Qq * DHh; idx += 256) {
    const int k = idx >> 5, d = idx & 31;
    const size_t ga = base + (size_t)k * Cc + d;
    Kf[k][d] = kh[ga] * 0.17677669529663687f;  // 1/sqrt(32) folded in
    Vb[k][d] = f2bf(vh[ga]);
  }
  __syncthreads();
  if (tid >= 150) return;
  const int q = halfq * 150 + tid;
  const float4* qp = reinterpret_cast<const float4*>(qh + base + (size_t)q * Cc);
  float4 qv[8];
  #pragma unroll
  for (int i = 0; i < 8; ++i) qv[i] = qp[i];

  float mx = -1e30f;
  for (int k = 0; k < Qq; ++k) {
    const float4* kp = reinterpret_cast<const float4*>(Kf[k]);
    float s = 0.f;
    #pragma unroll
    for (int i = 0; i < 8; ++i) {
      const float4 kv = kp[i];
      s = fmaf(qv[i].x, kv.x, s); s = fmaf(qv[i].y, kv.y, s);
      s = fmaf(qv[i].z, kv.z, s); s = fmaf(qv[i].w, kv.w, s);
    }
    mx = fmaxf(mx, s);
  }
  float sum = 0.f;
  float acc[32] = {};
  for (int k = 0; k < Qq; ++k) {
    const float4* kp = reinterpret_cast<const float4*>(Kf[k]);
    float s = 0.f;
    #pragma unroll
    for (int i = 0; i < 8; ++i) {
      const float4 kv = kp[i];
      s = fmaf(qv[i].x, kv.x, s); s = fmaf(qv[i].y, kv.y, s);
      s = fmaf(qv[i].z, kv.z, s); s = fmaf(qv[i].w, kv.w, s);
    }
    const float p = __expf(s - mx);
    sum += p;
    const u16* vp = Vb[k];
    #pragma unroll
    for (int d = 0; d < 32; ++d)
      acc[d] = fmaf(p, bf2f(vp[d]), acc[d]);
  }
  const float inv = 1.f / sum;
  float4* op = reinterpret_cast<float4*>(sa + base + (size_t)q * Cc);
  #pragma unroll
  for (int i = 0; i < 8; ++i) {
    float4 o;
    o.x = acc[i*4+0] * inv; o.y = acc[i*4+1] * inv;
    o.z = acc[i*4+2] * inv; o.w = acc[i*4+3] * inv;
    op[i] = o;
  }
}

// ---------------------------------------------------------------------------
// Fused residual-add + LayerNorm over C=256. One block (256 thr) per row.
// ---------------------------------------------------------------------------
__global__ __launch_bounds__(256) void ln_kernel(
    const float* __restrict__ x, const float* __restrict__ y,
    const float* __restrict__ g, const float* __restrict__ bta,
    float* __restrict__ out)
{
  const int row = blockIdx.x;
  const int t = threadIdx.x;
  const size_t idx = (size_t)row * Cc + t;
  const float v = x[idx] + y[idx];
  float s = v;
  #pragma unroll
  for (int o = 32; o; o >>= 1) s += __shfl_xor(s, o);
  __shared__ float ps[4], qs[4];
  const int wid = t >> 6, lane = t & 63;
  if (lane == 0) ps[wid] = s;
  __syncthreads();
  const float mean = (ps[0] + ps[1] + ps[2] + ps[3]) * (1.f / Cc);
  const float dv = v - mean;
  float s2 = dv * dv;
  #pragma unroll
  for (int o = 32; o; o >>= 1) s2 += __shfl_xor(s2, o);
  if (lane == 0) qs[wid] = s2;
  __syncthreads();
  const float var = (qs[0] + qs[1] + qs[2] + qs[3]) * (1.f / Cc);
  out[idx] = dv * rsqrtf(var + LN_EPS) * g[t] + bta[t];
}

// ---------------------------------------------------------------------------
// Deformable sampling: one wave per (b,q,h). lane = 32*half + d.
// ---------------------------------------------------------------------------
__global__ __launch_bounds__(256) void deform_kernel(
    const float* __restrict__ offb, const float* __restrict__ awl,
    const float* __restrict__ refp, const bf16* __restrict__ value,
    float* __restrict__ accp)
{
  const int gw = (int)((blockIdx.x * (size_t)blockDim.x + threadIdx.x) >> 6);
  if (gw >= Bb * Qq * NHh) return;
  const int lane = threadIdx.x & 63;
  const int h = gw % NHh;
  const int t = gw / NHh;
  const int qi = t % Qq;
  const int b = t / Qq;
  const int half = lane >> 5;
  const int d = lane & 31;

  const float* awp = awl + (size_t)(b * Qq + qi) * 128 + h * 16;
  float e[16];
  float mx = -1e30f;
  #pragma unroll
  for (int i = 0; i < 16; ++i) { e[i] = awp[i]; mx = fmaxf(mx, e[i]); }
  float s = 0.f;
  #pragma unroll
  for (int i = 0; i < 16; ++i) { e[i] = __expf(e[i] - mx); s += e[i]; }
  const float inv = 1.f / s;

  const float* offp = offb + (size_t)(b * Qq + qi) * Cc + h * 32;
  const float* rp = refp + (size_t)(b * Qq + qi) * 8;
  const int lH[4] = {128, 64, 32, 16};
  const int lW[4] = {128, 64, 32, 16};
  const int lS[4] = {0, 16384, 20480, 21504};

  float acc = 0.f;
  #pragma unroll
  for (int l = 0; l < 4; ++l) {
    const int Hl = lH[l], Wl = lW[l], st = lS[l];
    const float rx = rp[l * 2 + 0], ry = rp[l * 2 + 1];
    #pragma unroll
    for (int pp = 0; pp < 2; ++pp) {
      const int p = pp * 2 + half;
      const float ax = offp[l * 8 + p * 2 + 0];
      const float ay = offp[l * 8 + p * 2 + 1];
      const float x = (rx + ax / (float)Wl) * (float)Wl - 0.5f;
      const float y = (ry + ay / (float)Hl) * (float)Hl - 0.5f;
      const float x0f = floorf(x), y0f = floorf(y);
      const float wx = x - x0f, wy = y - y0f;
      const int x0 = (int)x0f, y0 = (int)y0f;
      const float wp = e[l * 4 + p] * inv;
      #pragma unroll
      for (int dy = 0; dy < 2; ++dy) {
        #pragma unroll
        for (int dx = 0; dx < 2; ++dx) {
          const int xi = x0 + dx, yi = y0 + dy;
          if (xi >= 0 && xi < Wl && yi >= 0 && yi < Hl) {
            const float w = (dx ? wx : 1.f - wx) * (dy ? wy : 1.f - wy);
            const bf16* vrow = value + ((size_t)(b * (size_t)Ss + st + yi * Wl + xi) * Cc + h * 32);
            acc = fmaf(wp * w, __bfloat162float(vrow[d]), acc);
          }
        }
      }
    }
  }
  acc += __shfl_xor(acc, 32);
  if (lane < 32) accp[(size_t)(b * Qq + qi) * Cc + h * 32 + d] = acc;
}

// ---------------------------------------------------------------------------
extern "C" void kernel_launch(void* const* d_in, const int* in_sizes, int n_in,
                              void* d_out, int out_size, void* d_ws, size_t ws_size,
                              hipStream_t stream) {
  const float* tgt   = (const float*)d_in[0];
  const float* qpos  = (const float*)d_in[2];
  const float* refp  = (const float*)d_in[3];
  const float* src   = (const float*)d_in[4];
  const float* wq = (const float*)d_in[8];   const float* bq = (const float*)d_in[9];
  const float* wk = (const float*)d_in[10];  const float* bk = (const float*)d_in[11];
  const float* wv = (const float*)d_in[12];  const float* bv = (const float*)d_in[13];
  const float* wo = (const float*)d_in[14];  const float* bo = (const float*)d_in[15];
  const float* w_off = (const float*)d_in[16];  const float* b_off = (const float*)d_in[17];
  const float* w_attn = (const float*)d_in[18]; const float* b_attn = (const float*)d_in[19];
  const float* w_val = (const float*)d_in[20];  const float* b_val = (const float*)d_in[21];
  const float* w_out = (const float*)d_in[22];  const float* b_out = (const float*)d_in[23];
  const float* w1 = (const float*)d_in[24];  const float* b1 = (const float*)d_in[25];
  const float* w2 = (const float*)d_in[26];  const float* b2 = (const float*)d_in[27];
  const float* ln2g = (const float*)d_in[28]; const float* ln2b = (const float*)d_in[29];
  const float* ln1g = (const float*)d_in[30]; const float* ln1b = (const float*)d_in[31];
  const float* ln3g = (const float*)d_in[32]; const float* ln3b = (const float*)d_in[33];

  float* fws = (float*)d_ws;
  const size_t NBQ = (size_t)Bb * Qq * Cc;  // 614400
  float* qhb  = fws;
  float* khb  = qhb  + NBQ;
  float* vhb  = khb  + NBQ;
  float* sab  = vhb  + NBQ;
  float* sapb = sab  + NBQ;
  float* tgt1 = sapb + NBQ;
  float* offb = tgt1 + NBQ;
  float* awlb = offb + NBQ;
  float* accb = awlb + NBQ;
  float* t2pb = accb + NBQ;
  float* t2nb = t2pb + NBQ;
  float* ffhb = t2nb + NBQ;   // 2400*1024
  float* ff2b = ffhb + (size_t)Bb * Qq * DFFf;
  bf16*  valb = (bf16*)(ff2b + NBQ);  // 174080*256 bf16

  const int MQ = Bb * Qq;  // 2400
  dim3 blk(256, 1, 1);
  dim3 gProj(Cc / 64, (MQ + 63) / 64);

  // self-attention projections (q = tgt + query_pos fused into GEMM A-load)
  gemm_tiled<false, float><<<gProj, blk, 0, stream>>>(tgt, qpos, wq, bq, qhb, MQ, Cc, Cc);
  gemm_tiled<false, float><<<gProj, blk, 0, stream>>>(tgt, qpos, wk, bk, khb, MQ, Cc, Cc);
  gemm_tiled<false, float><<<gProj, blk, 0, stream>>>(tgt, nullptr, wv, bv, vhb, MQ, Cc, Cc);
  attn2_kernel<<<dim3(Bb * NHh * 2), blk, 0, stream>>>(qhb, khb, vhb, sab);
  gemm_tiled<false, float><<<gProj, blk, 0, stream>>>(sab, nullptr, wo, bo, sapb, MQ, Cc, Cc);
  ln_kernel<<<dim3(MQ), blk, 0, stream>>>(tgt, sapb, ln2g, ln2b, tgt1);

  // value projection (dominant GEMM) with MFMA -> bf16
  value_gemm_mfma<<<dim3(2, (Bb * Ss) / 128), blk, 0, stream>>>(src, w_val, b_val, valb);

  // offsets + attention-weight logits (query = tgt1 + query_pos fused)
  gemm_tiled<false, float><<<gProj, blk, 0, stream>>>(tgt1, qpos, w_off, b_off, offb, MQ, Cc, Cc);
  gemm_tiled<false, float><<<dim3(128 / 64, (MQ + 63) / 64), blk, 0, stream>>>(
      tgt1, qpos, w_attn, b_attn, awlb, MQ, 128, Cc);

  deform_kernel<<<dim3(Bb * Qq * NHh / 4), blk, 0, stream>>>(offb, awlb, refp, valb, accb);

  gemm_tiled<false, float><<<gProj, blk, 0, stream>>>(accb, nullptr, w_out, b_out, t2pb, MQ, Cc, Cc);
  ln_kernel<<<dim3(MQ), blk, 0, stream>>>(tgt1, t2pb, ln1g, ln1b, t2nb);

  // FFN
  gemm_tiled<true, float><<<dim3(DFFf / 64, (MQ + 63) / 64), blk, 0, stream>>>(
      t2nb, nullptr, w1, b1, ffhb, MQ, DFFf, Cc);
  gemm_tiled<false, float><<<gProj, blk, 0, stream>>>(ffhb, nullptr, w2, b2, ff2b, MQ, Cc, DFFf);
  ln_kernel<<<dim3(MQ), blk, 0, stream>>>(t2nb, ff2b, ln3g, ln3b, (float*)d_out);
}

// Round 4
// 441.622 us; speedup vs baseline: 3.3996x; 1.1696x over previous
//
#include <hip/hip_runtime.h>
#include <hip/hip_bf16.h>
#include <math.h>

#define Bb   8
#define Qq   300
#define Cc   256
#define NHh  8
#define DHh  32
#define Ss   21760
#define DFFf 1024
#define LN_EPS 1e-5f

typedef __hip_bfloat16 bf16;
typedef unsigned short u16;
typedef unsigned int u32;
typedef __bf16 bf16x8_t __attribute__((ext_vector_type(8)));
typedef float f32x4_t __attribute__((ext_vector_type(4)));
typedef u16 u16x8_t __attribute__((ext_vector_type(8)));

__device__ inline u16 f2bf(float f) {
  union { float f; u32 u; } v; v.f = f;
  u32 u = v.u + 0x7fffu + ((v.u >> 16) & 1u);
  return (u16)(u >> 16);
}
__device__ inline float bf2f(u16 s) {
  union { u32 u; float f; } v; v.u = ((u32)s) << 16;
  return v.f;
}
__device__ inline float bfbits_lo(u32 w) {
  union { u32 u; float f; } v; v.u = w << 16;
  return v.f;
}
__device__ inline float bfbits_hi(u32 w) {
  union { u32 u; float f; } v; v.u = w & 0xffff0000u;
  return v.f;
}

template<typename T> __device__ inline T cvt_out(float v);
template<> __device__ inline float cvt_out<float>(float v){ return v; }
template<> __device__ inline bf16  cvt_out<bf16>(float v){ return __float2bfloat16(v); }

// ---------------------------------------------------------------------------
// Generic MFMA GEMM: out[M,N] = act((A (+A2)) @ W^T + bias), W is [N,K].
// fp32 inputs converted to bf16 while staging to LDS. 128x128 tile, BK=32,
// 4 waves each computing 64x64 via 4x4 mfma_f32_16x16x32_bf16.
// N, K compile-time (N % 128 == 0, K % 32 == 0); M runtime with bounds.
// ---------------------------------------------------------------------------
template<int N, int K, bool RELU, typename OutT>
__global__ __launch_bounds__(256) void gemm_mfma(
    const float* __restrict__ A, const float* __restrict__ A2,
    const float* __restrict__ W, const float* __restrict__ bias,
    OutT* __restrict__ out, int M)
{
  __shared__ u16 As[128][40];
  __shared__ u16 Bs[128][40];
  const int tid = threadIdx.x;
  const int m0 = blockIdx.y * 128;
  const int n0 = blockIdx.x * 128;
  const int w = tid >> 6, lane = tid & 63;
  const int wm = w >> 1, wn = w & 1;
  const int fr = lane & 15, fq = lane >> 4;
  const int sr = tid >> 1;            // staging row 0..127
  const int sk = (tid & 1) * 16;      // staging k offset {0,16}

  const int arow = (m0 + sr < M) ? (m0 + sr) : (M - 1);
  const float* aptr = A + (size_t)arow * K;
  const float* a2ptr = A2 ? (A2 + (size_t)arow * K) : nullptr;
  const float* bptr = W + (size_t)(n0 + sr) * K;

  f32x4_t acc[4][4];
  const f32x4_t zz = {0.f, 0.f, 0.f, 0.f};
  #pragma unroll
  for (int m = 0; m < 4; ++m)
    #pragma unroll
    for (int n = 0; n < 4; ++n) acc[m][n] = zz;

  for (int kt = 0; kt < K / 32; ++kt) {
    const int kg = kt * 32 + sk;
    const float4* ap = reinterpret_cast<const float4*>(aptr + kg);
    const float4* bp = reinterpret_cast<const float4*>(bptr + kg);
    float4 a0 = ap[0], a1 = ap[1], a2 = ap[2], a3 = ap[3];
    const float4 b0 = bp[0], b1 = bp[1], b2 = bp[2], b3 = bp[3];
    if (a2ptr) {
      const float4* a2p = reinterpret_cast<const float4*>(a2ptr + kg);
      float4 c0 = a2p[0], c1 = a2p[1], c2 = a2p[2], c3 = a2p[3];
      a0.x += c0.x; a0.y += c0.y; a0.z += c0.z; a0.w += c0.w;
      a1.x += c1.x; a1.y += c1.y; a1.z += c1.z; a1.w += c1.w;
      a2.x += c2.x; a2.y += c2.y; a2.z += c2.z; a2.w += c2.w;
      a3.x += c3.x; a3.y += c3.y; a3.z += c3.z; a3.w += c3.w;
    }
    const u16x8_t pa0 = { f2bf(a0.x), f2bf(a0.y), f2bf(a0.z), f2bf(a0.w),
                          f2bf(a1.x), f2bf(a1.y), f2bf(a1.z), f2bf(a1.w) };
    const u16x8_t pa1 = { f2bf(a2.x), f2bf(a2.y), f2bf(a2.z), f2bf(a2.w),
                          f2bf(a3.x), f2bf(a3.y), f2bf(a3.z), f2bf(a3.w) };
    const u16x8_t pb0 = { f2bf(b0.x), f2bf(b0.y), f2bf(b0.z), f2bf(b0.w),
                          f2bf(b1.x), f2bf(b1.y), f2bf(b1.z), f2bf(b1.w) };
    const u16x8_t pb1 = { f2bf(b2.x), f2bf(b2.y), f2bf(b2.z), f2bf(b2.w),
                          f2bf(b3.x), f2bf(b3.y), f2bf(b3.z), f2bf(b3.w) };
    __syncthreads();     // previous iteration's LDS reads complete
    *reinterpret_cast<u16x8_t*>(&As[sr][sk])     = pa0;
    *reinterpret_cast<u16x8_t*>(&As[sr][sk + 8]) = pa1;
    *reinterpret_cast<u16x8_t*>(&Bs[sr][sk])     = pb0;
    *reinterpret_cast<u16x8_t*>(&Bs[sr][sk + 8]) = pb1;
    __syncthreads();
    bf16x8_t af[4], bfr[4];
    #pragma unroll
    for (int m = 0; m < 4; ++m)
      af[m] = *reinterpret_cast<const bf16x8_t*>(&As[wm*64 + m*16 + fr][fq*8]);
    #pragma unroll
    for (int n = 0; n < 4; ++n)
      bfr[n] = *reinterpret_cast<const bf16x8_t*>(&Bs[wn*64 + n*16 + fr][fq*8]);
    #pragma unroll
    for (int m = 0; m < 4; ++m)
      #pragma unroll
      for (int n = 0; n < 4; ++n)
        acc[m][n] = __builtin_amdgcn_mfma_f32_16x16x32_bf16(af[m], bfr[n], acc[m][n], 0, 0, 0);
  }

  #pragma unroll
  for (int m = 0; m < 4; ++m) {
    const int row = m0 + wm*64 + m*16 + fq*4;
    #pragma unroll
    for (int n = 0; n < 4; ++n) {
      const int col = n0 + wn*64 + n*16 + fr;
      const float bc = bias[col];
      #pragma unroll
      for (int j = 0; j < 4; ++j) {
        if (row + j < M) {
          float v = acc[m][n][j] + bc;
          if (RELU) v = fmaxf(v, 0.f);
          out[(size_t)(row + j) * N + col] = cvt_out<OutT>(v);
        }
      }
    }
  }
}

// ---------------------------------------------------------------------------
// Self-attention v3b: wave-per-q-row. Block = (b, h, 16-row q-tile), 4 waves,
// each wave 4 rows. K fp32 (prescaled) + V bf16 staged in LDS.
// Vb padded to 304 rows, rows >=300 zeroed (PV reads keys up to 303 with p=0).
// Uniform control flow: q clamped, stores guarded — all waves hit all barriers.
// ---------------------------------------------------------------------------
__global__ __launch_bounds__(256) void attn3_kernel(
    const float* __restrict__ qh, const float* __restrict__ kh,
    const float* __restrict__ vh, float* __restrict__ sa)
{
  __shared__ float Kf[300][34];     // 39.8 KB, float2 reads
  __shared__ u16  Vb[304][36];      // 21.9 KB, rows 300..303 zero
  __shared__ float pbuf[4][304];    // 4.8 KB
  const int blk = blockIdx.x;
  const int qt = blk % 19;
  const int bh = blk / 19;
  const int h = bh & 7, b = bh >> 3;
  const int tid = threadIdx.x;
  const size_t base = ((size_t)b * Qq) * Cc + h * DHh;

  for (int idx = tid; idx < Qq * DHh; idx += 256) {
    const int k = idx >> 5, d = idx & 31;
    Kf[k][d] = kh[base + (size_t)k * Cc + d] * 0.17677669529663687f;  // 1/sqrt(32)
  }
  for (int idx = tid; idx < 304 * DHh; idx += 256) {
    const int k = idx >> 5, d = idx & 31;
    Vb[k][d] = (k < Qq) ? f2bf(vh[base + (size_t)k * Cc + d]) : (u16)0;
  }
  __syncthreads();

  const int wv = tid >> 6, lane = tid & 63;
  const int qtr = lane >> 4, dp = lane & 15;  // PV decomposition

  for (int r = 0; r < 4; ++r) {
    const int q0 = qt * 16 + wv * 4 + r;
    const int q = (q0 < Qq) ? q0 : (Qq - 1);   // clamp: uniform flow, guarded store
    const float* qp = qh + base + (size_t)q * Cc;
    float qv[32];
    #pragma unroll
    for (int i = 0; i < 8; ++i) {
      const float4 t = reinterpret_cast<const float4*>(qp)[i];
      qv[i*4+0] = t.x; qv[i*4+1] = t.y; qv[i*4+2] = t.z; qv[i*4+3] = t.w;
    }

    // ---- scores: 5 keys per lane ----
    float e[5];
    float mx = -1e30f;
    #pragma unroll
    for (int i = 0; i < 5; ++i) {
      const int k = lane + i * 64;
      if (k < Qq) {
        const float2* kp = reinterpret_cast<const float2*>(Kf[k]);
        float s = 0.f;
        #pragma unroll
        for (int d2 = 0; d2 < 16; ++d2) {
          const float2 kvp = kp[d2];
          s = fmaf(qv[2*d2], kvp.x, s);
          s = fmaf(qv[2*d2+1], kvp.y, s);
        }
        e[i] = s;
      } else {
        e[i] = -1e30f;
      }
      mx = fmaxf(mx, e[i]);
    }
    #pragma unroll
    for (int o = 32; o; o >>= 1) mx = fmaxf(mx, __shfl_xor(mx, o));
    float ssum = 0.f;
    #pragma unroll
    for (int i = 0; i < 5; ++i) { e[i] = __expf(e[i] - mx); ssum += e[i]; }
    #pragma unroll
    for (int o = 32; o; o >>= 1) ssum += __shfl_xor(ssum, o);
    const float inv = 1.f / ssum;
    #pragma unroll
    for (int i = 0; i < 5; ++i) {
      const int k = lane + i * 64;
      if (k < 304) pbuf[wv][k] = (k < Qq) ? e[i] * inv : 0.f;
    }
    __syncthreads();   // pbuf writes visible (uniform barrier)

    // ---- PV: quarter qtr handles keys qtr*76..qtr*76+75, dims 2dp,2dp+1 ----
    float accA = 0.f, accB = 0.f;
    const float* prow = pbuf[wv] + qtr * 76;
    #pragma unroll 4
    for (int j4 = 0; j4 < 19; ++j4) {
      const float4 pv4 = *reinterpret_cast<const float4*>(prow + j4 * 4);
      const int kb = qtr * 76 + j4 * 4;
      const u32 v0 = *reinterpret_cast<const u32*>(&Vb[kb + 0][2*dp]);
      const u32 v1 = *reinterpret_cast<const u32*>(&Vb[kb + 1][2*dp]);
      const u32 v2 = *reinterpret_cast<const u32*>(&Vb[kb + 2][2*dp]);
      const u32 v3 = *reinterpret_cast<const u32*>(&Vb[kb + 3][2*dp]);
      accA = fmaf(pv4.x, bfbits_lo(v0), accA); accB = fmaf(pv4.x, bfbits_hi(v0), accB);
      accA = fmaf(pv4.y, bfbits_lo(v1), accA); accB = fmaf(pv4.y, bfbits_hi(v1), accB);
      accA = fmaf(pv4.z, bfbits_lo(v2), accA); accB = fmaf(pv4.z, bfbits_hi(v2), accB);
      accA = fmaf(pv4.w, bfbits_lo(v3), accA); accB = fmaf(pv4.w, bfbits_hi(v3), accB);
    }
    accA += __shfl_xor(accA, 16); accA += __shfl_xor(accA, 32);
    accB += __shfl_xor(accB, 16); accB += __shfl_xor(accB, 32);
    if (q0 < Qq && lane < 16) {
      float2 st; st.x = accA; st.y = accB;
      *reinterpret_cast<float2*>(sa + base + (size_t)q * Cc + 2 * dp) = st;
    }
    __syncthreads();  // pbuf safe to rewrite next r
  }
}

// ---------------------------------------------------------------------------
// Fused residual-add + LayerNorm over C=256. One block (256 thr) per row.
// ---------------------------------------------------------------------------
__global__ __launch_bounds__(256) void ln_kernel(
    const float* __restrict__ x, const float* __restrict__ y,
    const float* __restrict__ g, const float* __restrict__ bta,
    float* __restrict__ out)
{
  const int row = blockIdx.x;
  const int t = threadIdx.x;
  const size_t idx = (size_t)row * Cc + t;
  const float v = x[idx] + y[idx];
  float s = v;
  #pragma unroll
  for (int o = 32; o; o >>= 1) s += __shfl_xor(s, o);
  __shared__ float ps[4], qs[4];
  const int wid = t >> 6, lane = t & 63;
  if (lane == 0) ps[wid] = s;
  __syncthreads();
  const float mean = (ps[0] + ps[1] + ps[2] + ps[3]) * (1.f / Cc);
  const float dv = v - mean;
  float s2 = dv * dv;
  #pragma unroll
  for (int o = 32; o; o >>= 1) s2 += __shfl_xor(s2, o);
  if (lane == 0) qs[wid] = s2;
  __syncthreads();
  const float var = (qs[0] + qs[1] + qs[2] + qs[3]) * (1.f / Cc);
  out[idx] = dv * rsqrtf(var + LN_EPS) * g[t] + bta[t];
}

// ---------------------------------------------------------------------------
// Deformable sampling: one wave per (b,q,h). lane = 32*half + d.
// ---------------------------------------------------------------------------
__global__ __launch_bounds__(256) void deform_kernel(
    const float* __restrict__ offb, const float* __restrict__ awl,
    const float* __restrict__ refp, const bf16* __restrict__ value,
    float* __restrict__ accp)
{
  const int gw = (int)((blockIdx.x * (size_t)blockDim.x + threadIdx.x) >> 6);
  if (gw >= Bb * Qq * NHh) return;
  const int lane = threadIdx.x & 63;
  const int h = gw % NHh;
  const int t = gw / NHh;
  const int qi = t % Qq;
  const int b = t / Qq;
  const int half = lane >> 5;
  const int d = lane & 31;

  const float* awp = awl + (size_t)(b * Qq + qi) * 128 + h * 16;
  float e[16];
  float mx = -1e30f;
  #pragma unroll
  for (int i = 0; i < 16; ++i) { e[i] = awp[i]; mx = fmaxf(mx, e[i]); }
  float s = 0.f;
  #pragma unroll
  for (int i = 0; i < 16; ++i) { e[i] = __expf(e[i] - mx); s += e[i]; }
  const float inv = 1.f / s;

  const float* offp = offb + (size_t)(b * Qq + qi) * Cc + h * 32;
  const float* rp = refp + (size_t)(b * Qq + qi) * 8;
  const int lH[4] = {128, 64, 32, 16};
  const int lW[4] = {128, 64, 32, 16};
  const int lS[4] = {0, 16384, 20480, 21504};

  float acc = 0.f;
  #pragma unroll
  for (int l = 0; l < 4; ++l) {
    const int Hl = lH[l], Wl = lW[l], st = lS[l];
    const float rx = rp[l * 2 + 0], ry = rp[l * 2 + 1];
    #pragma unroll
    for (int pp = 0; pp < 2; ++pp) {
      const int p = pp * 2 + half;
      const float ax = offp[l * 8 + p * 2 + 0];
      const float ay = offp[l * 8 + p * 2 + 1];
      const float x = (rx + ax / (float)Wl) * (float)Wl - 0.5f;
      const float y = (ry + ay / (float)Hl) * (float)Hl - 0.5f;
      const float x0f = floorf(x), y0f = floorf(y);
      const float wx = x - x0f, wy = y - y0f;
      const int x0 = (int)x0f, y0 = (int)y0f;
      const float wp = e[l * 4 + p] * inv;
      #pragma unroll
      for (int dy = 0; dy < 2; ++dy) {
        #pragma unroll
        for (int dx = 0; dx < 2; ++dx) {
          const int xi = x0 + dx, yi = y0 + dy;
          if (xi >= 0 && xi < Wl && yi >= 0 && yi < Hl) {
            const float w = (dx ? wx : 1.f - wx) * (dy ? wy : 1.f - wy);
            const bf16* vrow = value + ((size_t)(b * (size_t)Ss + st + yi * Wl + xi) * Cc + h * 32);
            acc = fmaf(wp * w, __bfloat162float(vrow[d]), acc);
          }
        }
      }
    }
  }
  acc += __shfl_xor(acc, 32);
  if (lane < 32) accp[(size_t)(b * Qq + qi) * Cc + h * 32 + d] = acc;
}

// ---------------------------------------------------------------------------
extern "C" void kernel_launch(void* const* d_in, const int* in_sizes, int n_in,
                              void* d_out, int out_size, void* d_ws, size_t ws_size,
                              hipStream_t stream) {
  const float* tgt   = (const float*)d_in[0];
  const float* qpos  = (const float*)d_in[2];
  const float* refp  = (const float*)d_in[3];
  const float* src   = (const float*)d_in[4];
  const float* wq = (const float*)d_in[8];   const float* bq = (const float*)d_in[9];
  const float* wk = (const float*)d_in[10];  const float* bk = (const float*)d_in[11];
  const float* wv = (const float*)d_in[12];  const float* bv = (const float*)d_in[13];
  const float* wo = (const float*)d_in[14];  const float* bo = (const float*)d_in[15];
  const float* w_off = (const float*)d_in[16];  const float* b_off = (const float*)d_in[17];
  const float* w_attn = (const float*)d_in[18]; const float* b_attn = (const float*)d_in[19];
  const float* w_val = (const float*)d_in[20];  const float* b_val = (const float*)d_in[21];
  const float* w_out = (const float*)d_in[22];  const float* b_out = (const float*)d_in[23];
  const float* w1 = (const float*)d_in[24];  const float* b1 = (const float*)d_in[25];
  const float* w2 = (const float*)d_in[26];  const float* b2 = (const float*)d_in[27];
  const float* ln2g = (const float*)d_in[28]; const float* ln2b = (const float*)d_in[29];
  const float* ln1g = (const float*)d_in[30]; const float* ln1b = (const float*)d_in[31];
  const float* ln3g = (const float*)d_in[32]; const float* ln3b = (const float*)d_in[33];

  float* fws = (float*)d_ws;
  const size_t NBQ = (size_t)Bb * Qq * Cc;  // 614400
  float* qhb  = fws;
  float* khb  = qhb  + NBQ;
  float* vhb  = khb  + NBQ;
  float* sab  = vhb  + NBQ;
  float* sapb = sab  + NBQ;
  float* tgt1 = sapb + NBQ;
  float* offb = tgt1 + NBQ;
  float* awlb = offb + NBQ;
  float* accb = awlb + NBQ;
  float* t2pb = accb + NBQ;
  float* t2nb = t2pb + NBQ;
  float* ffhb = t2nb + NBQ;   // 2400*1024
  float* ff2b = ffhb + (size_t)Bb * Qq * DFFf;
  bf16*  valb = (bf16*)(ff2b + NBQ);  // 174080*256 bf16

  const int MQ = Bb * Qq;  // 2400
  dim3 blk(256, 1, 1);
  dim3 gP(2, 19);          // N=256 GEMMs on M=2400

  gemm_mfma<256, 256, false, float><<<gP, blk, 0, stream>>>(tgt, qpos, wq, bq, qhb, MQ);
  gemm_mfma<256, 256, false, float><<<gP, blk, 0, stream>>>(tgt, qpos, wk, bk, khb, MQ);
  gemm_mfma<256, 256, false, float><<<gP, blk, 0, stream>>>(tgt, nullptr, wv, bv, vhb, MQ);
  attn3_kernel<<<dim3(Bb * NHh * 19), blk, 0, stream>>>(qhb, khb, vhb, sab);
  gemm_mfma<256, 256, false, float><<<gP, blk, 0, stream>>>(sab, nullptr, wo, bo, sapb, MQ);
  ln_kernel<<<dim3(MQ), blk, 0, stream>>>(tgt, sapb, ln2g, ln2b, tgt1);

  // value projection (dominant GEMM) -> bf16
  gemm_mfma<256, 256, false, bf16><<<dim3(2, (Bb * Ss) / 128), blk, 0, stream>>>(
      src, nullptr, w_val, b_val, valb, Bb * Ss);

  gemm_mfma<256, 256, false, float><<<gP, blk, 0, stream>>>(tgt1, qpos, w_off, b_off, offb, MQ);
  gemm_mfma<128, 256, false, float><<<dim3(1, 19), blk, 0, stream>>>(tgt1, qpos, w_attn, b_attn, awlb, MQ);

  deform_kernel<<<dim3(Bb * Qq * NHh / 4), blk, 0, stream>>>(offb, awlb, refp, valb, accb);

  gemm_mfma<256, 256, false, float><<<gP, blk, 0, stream>>>(accb, nullptr, w_out, b_out, t2pb, MQ);
  ln_kernel<<<dim3(MQ), blk, 0, stream>>>(tgt1, t2pb, ln1g, ln1b, t2nb);

  // FFN
  gemm_mfma<1024, 256, true, float><<<dim3(8, 19), blk, 0, stream>>>(t2nb, nullptr, w1, b1, ffhb, MQ);
  gemm_mfma<256, 1024, false, float><<<gP, blk, 0, stream>>>(ffhb, nullptr, w2, b2, ff2b, MQ);
  ln_kernel<<<dim3(MQ), blk, 0, stream>>>(t2nb, ff2b, ln3g, ln3b, (float*)d_out);
}

// Round 5
// 289.514 us; speedup vs baseline: 5.1857x; 1.5254x over previous
//
#include <hip/hip_runtime.h>
#include <hip/hip_bf16.h>
#include <math.h>

#define Bb   8
#define Qq   300
#define Cc   256
#define NHh  8
#define DHh  32
#define Ss   21760
#define DFFf 1024
#define LN_EPS 1e-5f

typedef __hip_bfloat16 bf16;
typedef unsigned short u16;
typedef unsigned int u32;
typedef __bf16 bf16x8_t __attribute__((ext_vector_type(8)));
typedef float f32x4_t __attribute__((ext_vector_type(4)));

__device__ inline u16 f2bf(float f) {
  union { float f; u32 u; } v; v.f = f;
  u32 u = v.u + 0x7fffu + ((v.u >> 16) & 1u);
  return (u16)(u >> 16);
}
__device__ inline float bfbits_lo(u32 w) {
  union { u32 u; float f; } v; v.u = w << 16;
  return v.f;
}
__device__ inline float bfbits_hi(u32 w) {
  union { u32 u; float f; } v; v.u = w & 0xffff0000u;
  return v.f;
}

// Packed-weight fragment bases (in 512-elem frag units).
// Layout per frag (gnf, kt): elem (lane, j) = W[gnf*16 + (lane&15)][kt*32 + (lane>>4)*8 + j]
#define FR_WQ    0
#define FR_WK    128
#define FR_WV    256
#define FR_WO    384
#define FR_WVAL  512
#define FR_WOFF  640
#define FR_WATTN 768
#define FR_WOUT  832
#define FR_W1    960
#define FR_W2    1472
#define FR_TOTAL 1984

// ---------------------------------------------------------------------------
// Pack all weights fp32 [N][K] -> bf16 MFMA B-fragment layout. 1 wave = 1 frag.
// ---------------------------------------------------------------------------
__global__ __launch_bounds__(256) void pack_weights(
    const float* __restrict__ wq, const float* __restrict__ wk,
    const float* __restrict__ wv, const float* __restrict__ wo,
    const float* __restrict__ wval, const float* __restrict__ woff,
    const float* __restrict__ wattn, const float* __restrict__ wout,
    const float* __restrict__ w1, const float* __restrict__ w2,
    __bf16* __restrict__ Bpk)
{
  const int gw = (int)((blockIdx.x * blockDim.x + threadIdx.x) >> 6);
  const int lane = threadIdx.x & 63;
  if (gw >= FR_TOTAL) return;
  const float* W; int KT, base;
  if      (gw < FR_WK)   { W = wq;    KT = 8;  base = FR_WQ; }
  else if (gw < FR_WV)   { W = wk;    KT = 8;  base = FR_WK; }
  else if (gw < FR_WO)   { W = wv;    KT = 8;  base = FR_WV; }
  else if (gw < FR_WVAL) { W = wo;    KT = 8;  base = FR_WO; }
  else if (gw < FR_WOFF) { W = wval;  KT = 8;  base = FR_WVAL; }
  else if (gw < FR_WATTN){ W = woff;  KT = 8;  base = FR_WOFF; }
  else if (gw < FR_WOUT) { W = wattn; KT = 8;  base = FR_WATTN; }
  else if (gw < FR_W1)   { W = wout;  KT = 8;  base = FR_WOUT; }
  else if (gw < FR_W2)   { W = w1;    KT = 8;  base = FR_W1; }
  else                   { W = w2;    KT = 32; base = FR_W2; }
  const int f = gw - base;
  const int nf = f / KT, kt = f % KT;
  const int col = nf * 16 + (lane & 15);
  const int k0 = kt * 32 + (lane >> 4) * 8;
  const int K = KT * 32;
  const float4 a = *reinterpret_cast<const float4*>(W + (size_t)col * K + k0);
  const float4 b = *reinterpret_cast<const float4*>(W + (size_t)col * K + k0 + 4);
  bf16x8_t p = { (__bf16)a.x, (__bf16)a.y, (__bf16)a.z, (__bf16)a.w,
                 (__bf16)b.x, (__bf16)b.y, (__bf16)b.z, (__bf16)b.w };
  *reinterpret_cast<bf16x8_t*>(Bpk + ((size_t)gw * 64 + lane) * 8) = p;
}

// ---------------------------------------------------------------------------
// Small-GEMM body: BM=64, BN=128, 256 threads (4 waves, wave tile 32x64).
// A fp32 staged->bf16 in LDS; B direct from packed-fragment global (L2-hot).
// ---------------------------------------------------------------------------
template<int KT, bool RELU>
__device__ __forceinline__ void gemm64_body(
    __bf16 (*As)[40],
    const float* __restrict__ A, const float* __restrict__ A2,
    const __bf16* __restrict__ Wp, const float* __restrict__ bias,
    float* __restrict__ out, int M, int N, int m0, int n0)
{
  const int tid = threadIdx.x;
  const int w = tid >> 6, lane = tid & 63;
  const int wm = w >> 1, wn = w & 1;
  const int fr = lane & 15, fq = lane >> 4;
  const int sr = tid >> 2, sk = (tid & 3) * 8;
  constexpr int K = KT * 32;

  const int arow = (m0 + sr < M) ? (m0 + sr) : (M - 1);
  const float* aptr = A + (size_t)arow * K;
  const float* a2ptr = A2 ? (A2 + (size_t)arow * K) : nullptr;
  const __bf16* wp = Wp + (size_t)((n0 >> 4) + wn * 4) * KT * 512 + (size_t)lane * 8;

  f32x4_t acc[2][4];
  const f32x4_t zz = {0.f, 0.f, 0.f, 0.f};
  #pragma unroll
  for (int m = 0; m < 2; ++m)
    #pragma unroll
    for (int n = 0; n < 4; ++n) acc[m][n] = zz;

  for (int kt = 0; kt < KT; ++kt) {
    const int kg = kt * 32 + sk;
    float4 a0 = *reinterpret_cast<const float4*>(aptr + kg);
    float4 a1 = *reinterpret_cast<const float4*>(aptr + kg + 4);
    if (a2ptr) {
      const float4 c0 = *reinterpret_cast<const float4*>(a2ptr + kg);
      const float4 c1 = *reinterpret_cast<const float4*>(a2ptr + kg + 4);
      a0.x += c0.x; a0.y += c0.y; a0.z += c0.z; a0.w += c0.w;
      a1.x += c1.x; a1.y += c1.y; a1.z += c1.z; a1.w += c1.w;
    }
    const bf16x8_t pa = { (__bf16)a0.x, (__bf16)a0.y, (__bf16)a0.z, (__bf16)a0.w,
                          (__bf16)a1.x, (__bf16)a1.y, (__bf16)a1.z, (__bf16)a1.w };
    bf16x8_t bfr[4];
    #pragma unroll
    for (int n = 0; n < 4; ++n)
      bfr[n] = *reinterpret_cast<const bf16x8_t*>(wp + (size_t)(n * KT + kt) * 512);
    __syncthreads();    // previous iteration's LDS reads complete
    *reinterpret_cast<bf16x8_t*>(&As[sr][sk]) = pa;
    __syncthreads();
    bf16x8_t af[2];
    #pragma unroll
    for (int m = 0; m < 2; ++m)
      af[m] = *reinterpret_cast<const bf16x8_t*>(&As[wm*32 + m*16 + fr][fq*8]);
    #pragma unroll
    for (int m = 0; m < 2; ++m)
      #pragma unroll
      for (int n = 0; n < 4; ++n)
        acc[m][n] = __builtin_amdgcn_mfma_f32_16x16x32_bf16(af[m], bfr[n], acc[m][n], 0, 0, 0);
  }

  #pragma unroll
  for (int m = 0; m < 2; ++m) {
    const int row = m0 + wm*32 + m*16 + fq*4;
    #pragma unroll
    for (int n = 0; n < 4; ++n) {
      const int col = n0 + wn*64 + n*16 + fr;
      const float bc = bias[col];
      #pragma unroll
      for (int j = 0; j < 4; ++j) {
        if (row + j < M) {
          float v = acc[m][n][j] + bc;
          if (RELU) v = fmaxf(v, 0.f);
          out[(size_t)(row + j) * N + col] = v;
        }
      }
    }
  }
}

template<int KT, bool RELU>
__global__ __launch_bounds__(256) void gemm64(
    const float* __restrict__ A, const float* __restrict__ A2,
    const __bf16* __restrict__ Wp, const float* __restrict__ bias,
    float* __restrict__ out, int M, int N)
{
  __shared__ __bf16 As[64][40];
  gemm64_body<KT, RELU>(As, A, A2, Wp, bias, out, M, N, blockIdx.y * 64, blockIdx.x * 128);
}

// Fused q/k/v projections: blockIdx.x 0..5 -> (sel = x>>1, n0 = (x&1)*128)
__global__ __launch_bounds__(256) void gemm_qkv(
    const float* __restrict__ tgt, const float* __restrict__ qpos,
    const __bf16* __restrict__ Bpk,
    const float* __restrict__ bq, const float* __restrict__ bk, const float* __restrict__ bv,
    float* __restrict__ qhb, float* __restrict__ khb, float* __restrict__ vhb, int M)
{
  __shared__ __bf16 As[64][40];
  const int sel = blockIdx.x >> 1;
  const int n0 = (blockIdx.x & 1) * 128;
  const __bf16* Wp; const float* bias; float* out; const float* A2;
  if (sel == 0)      { Wp = Bpk + (size_t)FR_WQ * 512; bias = bq; out = qhb; A2 = qpos; }
  else if (sel == 1) { Wp = Bpk + (size_t)FR_WK * 512; bias = bk; out = khb; A2 = qpos; }
  else               { Wp = Bpk + (size_t)FR_WV * 512; bias = bv; out = vhb; A2 = nullptr; }
  gemm64_body<8, false>(As, tgt, A2, Wp, bias, out, M, 256, blockIdx.y * 64, n0);
}

// Fused offset + attention-logit projections: blockIdx.x 0,1 -> w_off; 2 -> w_attn
__global__ __launch_bounds__(256) void gemm_offattn(
    const float* __restrict__ tgt1, const float* __restrict__ qpos,
    const __bf16* __restrict__ Bpk,
    const float* __restrict__ b_off, const float* __restrict__ b_attn,
    float* __restrict__ offb, float* __restrict__ awlb, int M)
{
  __shared__ __bf16 As[64][40];
  const int bx = blockIdx.x;
  if (bx < 2)
    gemm64_body<8, false>(As, tgt1, qpos, Bpk + (size_t)FR_WOFF * 512, b_off, offb,
                          M, 256, blockIdx.y * 64, bx * 128);
  else
    gemm64_body<8, false>(As, tgt1, qpos, Bpk + (size_t)FR_WATTN * 512, b_attn, awlb,
                          M, 128, blockIdx.y * 64, 0);
}

// ---------------------------------------------------------------------------
// Value projection: 512 threads, 128x256 tile (full N), B direct from packed.
// out bf16. M = 174080 (exact multiple of 128).
// ---------------------------------------------------------------------------
__global__ __launch_bounds__(512) void value_gemm(
    const float* __restrict__ A, const __bf16* __restrict__ Wp,
    const float* __restrict__ bias, bf16* __restrict__ out)
{
  __shared__ __bf16 As[128][40];
  const int tid = threadIdx.x;
  const int w = tid >> 6, lane = tid & 63;
  const int wm = w >> 2, wn = w & 3;
  const int fr = lane & 15, fq = lane >> 4;
  const int sr = tid >> 2, sk = (tid & 3) * 8;
  const int m0 = blockIdx.x * 128;

  const float* aptr = A + (size_t)(m0 + sr) * 256;
  const __bf16* wp = Wp + (size_t)(wn * 4) * 8 * 512 + (size_t)lane * 8;

  f32x4_t acc[4][4];
  const f32x4_t zz = {0.f, 0.f, 0.f, 0.f};
  #pragma unroll
  for (int m = 0; m < 4; ++m)
    #pragma unroll
    for (int n = 0; n < 4; ++n) acc[m][n] = zz;

  for (int kt = 0; kt < 8; ++kt) {
    const int kg = kt * 32 + sk;
    const float4 a0 = *reinterpret_cast<const float4*>(aptr + kg);
    const float4 a1 = *reinterpret_cast<const float4*>(aptr + kg + 4);
    const bf16x8_t pa = { (__bf16)a0.x, (__bf16)a0.y, (__bf16)a0.z, (__bf16)a0.w,
                          (__bf16)a1.x, (__bf16)a1.y, (__bf16)a1.z, (__bf16)a1.w };
    bf16x8_t bfr[4];
    #pragma unroll
    for (int n = 0; n < 4; ++n)
      bfr[n] = *reinterpret_cast<const bf16x8_t*>(wp + (size_t)(n * 8 + kt) * 512);
    __syncthreads();
    *reinterpret_cast<bf16x8_t*>(&As[sr][sk]) = pa;
    __syncthreads();
    bf16x8_t af[4];
    #pragma unroll
    for (int m = 0; m < 4; ++m)
      af[m] = *reinterpret_cast<const bf16x8_t*>(&As[wm*64 + m*16 + fr][fq*8]);
    #pragma unroll
    for (int m = 0; m < 4; ++m)
      #pragma unroll
      for (int n = 0; n < 4; ++n)
        acc[m][n] = __builtin_amdgcn_mfma_f32_16x16x32_bf16(af[m], bfr[n], acc[m][n], 0, 0, 0);
  }

  #pragma unroll
  for (int m = 0; m < 4; ++m) {
    const int row = m0 + wm*64 + m*16 + fq*4;
    #pragma unroll
    for (int n = 0; n < 4; ++n) {
      const int col = wn*64 + n*16 + fr;
      const float bc = bias[col];
      #pragma unroll
      for (int j = 0; j < 4; ++j)
        out[(size_t)(row + j) * 256 + col] = __float2bfloat16(acc[m][n][j] + bc);
    }
  }
}

// ---------------------------------------------------------------------------
// Self-attention: wave-per-q-row. Block = (b, h, 16-row q-tile), 4 waves.
// ---------------------------------------------------------------------------
__global__ __launch_bounds__(256) void attn3_kernel(
    const float* __restrict__ qh, const float* __restrict__ kh,
    const float* __restrict__ vh, float* __restrict__ sa)
{
  __shared__ float Kf[300][34];
  __shared__ u16  Vb[304][36];
  __shared__ float pbuf[4][304];
  const int blk = blockIdx.x;
  const int qt = blk % 19;
  const int bh = blk / 19;
  const int h = bh & 7, b = bh >> 3;
  const int tid = threadIdx.x;
  const size_t base = ((size_t)b * Qq) * Cc + h * DHh;

  for (int idx = tid; idx < Qq * DHh; idx += 256) {
    const int k = idx >> 5, d = idx & 31;
    Kf[k][d] = kh[base + (size_t)k * Cc + d] * 0.17677669529663687f;
  }
  for (int idx = tid; idx < 304 * DHh; idx += 256) {
    const int k = idx >> 5, d = idx & 31;
    Vb[k][d] = (k < Qq) ? f2bf(vh[base + (size_t)k * Cc + d]) : (u16)0;
  }
  __syncthreads();

  const int wv = tid >> 6, lane = tid & 63;
  const int qtr = lane >> 4, dp = lane & 15;

  for (int r = 0; r < 4; ++r) {
    const int q0 = qt * 16 + wv * 4 + r;
    const int q = (q0 < Qq) ? q0 : (Qq - 1);
    const float* qp = qh + base + (size_t)q * Cc;
    float qv[32];
    #pragma unroll
    for (int i = 0; i < 8; ++i) {
      const float4 t = reinterpret_cast<const float4*>(qp)[i];
      qv[i*4+0] = t.x; qv[i*4+1] = t.y; qv[i*4+2] = t.z; qv[i*4+3] = t.w;
    }

    float e[5];
    float mx = -1e30f;
    #pragma unroll
    for (int i = 0; i < 5; ++i) {
      const int k = lane + i * 64;
      if (k < Qq) {
        const float2* kp = reinterpret_cast<const float2*>(Kf[k]);
        float s = 0.f;
        #pragma unroll
        for (int d2 = 0; d2 < 16; ++d2) {
          const float2 kvp = kp[d2];
          s = fmaf(qv[2*d2], kvp.x, s);
          s = fmaf(qv[2*d2+1], kvp.y, s);
        }
        e[i] = s;
      } else {
        e[i] = -1e30f;
      }
      mx = fmaxf(mx, e[i]);
    }
    #pragma unroll
    for (int o = 32; o; o >>= 1) mx = fmaxf(mx, __shfl_xor(mx, o));
    float ssum = 0.f;
    #pragma unroll
    for (int i = 0; i < 5; ++i) { e[i] = __expf(e[i] - mx); ssum += e[i]; }
    #pragma unroll
    for (int o = 32; o; o >>= 1) ssum += __shfl_xor(ssum, o);
    const float inv = 1.f / ssum;
    #pragma unroll
    for (int i = 0; i < 5; ++i) {
      const int k = lane + i * 64;
      if (k < 304) pbuf[wv][k] = (k < Qq) ? e[i] * inv : 0.f;
    }
    __syncthreads();

    float accA = 0.f, accB = 0.f;
    const float* prow = pbuf[wv] + qtr * 76;
    #pragma unroll 4
    for (int j4 = 0; j4 < 19; ++j4) {
      const float4 pv4 = *reinterpret_cast<const float4*>(prow + j4 * 4);
      const int kb = qtr * 76 + j4 * 4;
      const u32 v0 = *reinterpret_cast<const u32*>(&Vb[kb + 0][2*dp]);
      const u32 v1 = *reinterpret_cast<const u32*>(&Vb[kb + 1][2*dp]);
      const u32 v2 = *reinterpret_cast<const u32*>(&Vb[kb + 2][2*dp]);
      const u32 v3 = *reinterpret_cast<const u32*>(&Vb[kb + 3][2*dp]);
      accA = fmaf(pv4.x, bfbits_lo(v0), accA); accB = fmaf(pv4.x, bfbits_hi(v0), accB);
      accA = fmaf(pv4.y, bfbits_lo(v1), accA); accB = fmaf(pv4.y, bfbits_hi(v1), accB);
      accA = fmaf(pv4.z, bfbits_lo(v2), accA); accB = fmaf(pv4.z, bfbits_hi(v2), accB);
      accA = fmaf(pv4.w, bfbits_lo(v3), accA); accB = fmaf(pv4.w, bfbits_hi(v3), accB);
    }
    accA += __shfl_xor(accA, 16); accA += __shfl_xor(accA, 32);
    accB += __shfl_xor(accB, 16); accB += __shfl_xor(accB, 32);
    if (q0 < Qq && lane < 16) {
      float2 st; st.x = accA; st.y = accB;
      *reinterpret_cast<float2*>(sa + base + (size_t)q * Cc + 2 * dp) = st;
    }
    __syncthreads();
  }
}

// ---------------------------------------------------------------------------
// Fused residual-add + LayerNorm over C=256. One block (256 thr) per row.
// ---------------------------------------------------------------------------
__global__ __launch_bounds__(256) void ln_kernel(
    const float* __restrict__ x, const float* __restrict__ y,
    const float* __restrict__ g, const float* __restrict__ bta,
    float* __restrict__ out)
{
  const int row = blockIdx.x;
  const int t = threadIdx.x;
  const size_t idx = (size_t)row * Cc + t;
  const float v = x[idx] + y[idx];
  float s = v;
  #pragma unroll
  for (int o = 32; o; o >>= 1) s += __shfl_xor(s, o);
  __shared__ float ps[4], qs[4];
  const int wid = t >> 6, lane = t & 63;
  if (lane == 0) ps[wid] = s;
  __syncthreads();
  const float mean = (ps[0] + ps[1] + ps[2] + ps[3]) * (1.f / Cc);
  const float dv = v - mean;
  float s2 = dv * dv;
  #pragma unroll
  for (int o = 32; o; o >>= 1) s2 += __shfl_xor(s2, o);
  if (lane == 0) qs[wid] = s2;
  __syncthreads();
  const float var = (qs[0] + qs[1] + qs[2] + qs[3]) * (1.f / Cc);
  out[idx] = dv * rsqrtf(var + LN_EPS) * g[t] + bta[t];
}

// ---------------------------------------------------------------------------
// Deformable sampling: one wave per (b,q,h). lane = 32*half + d.
// ---------------------------------------------------------------------------
__global__ __launch_bounds__(256) void deform_kernel(
    const float* __restrict__ offb, const float* __restrict__ awl,
    const float* __restrict__ refp, const bf16* __restrict__ value,
    float* __restrict__ accp)
{
  const int gw = (int)((blockIdx.x * (size_t)blockDim.x + threadIdx.x) >> 6);
  if (gw >= Bb * Qq * NHh) return;
  const int lane = threadIdx.x & 63;
  const int h = gw % NHh;
  const int t = gw / NHh;
  const int qi = t % Qq;
  const int b = t / Qq;
  const int half = lane >> 5;
  const int d = lane & 31;

  const float* awp = awl + (size_t)(b * Qq + qi) * 128 + h * 16;
  float e[16];
  float mx = -1e30f;
  #pragma unroll
  for (int i = 0; i < 16; ++i) { e[i] = awp[i]; mx = fmaxf(mx, e[i]); }
  float s = 0.f;
  #pragma unroll
  for (int i = 0; i < 16; ++i) { e[i] = __expf(e[i] - mx); s += e[i]; }
  const float inv = 1.f / s;

  const float* offp = offb + (size_t)(b * Qq + qi) * Cc + h * 32;
  const float* rp = refp + (size_t)(b * Qq + qi) * 8;
  const int lH[4] = {128, 64, 32, 16};
  const int lW[4] = {128, 64, 32, 16};
  const int lS[4] = {0, 16384, 20480, 21504};

  float acc = 0.f;
  #pragma unroll
  for (int l = 0; l < 4; ++l) {
    const int Hl = lH[l], Wl = lW[l], st = lS[l];
    const float rx = rp[l * 2 + 0], ry = rp[l * 2 + 1];
    #pragma unroll
    for (int pp = 0; pp < 2; ++pp) {
      const int p = pp * 2 + half;
      const float ax = offp[l * 8 + p * 2 + 0];
      const float ay = offp[l * 8 + p * 2 + 1];
      const float x = (rx + ax / (float)Wl) * (float)Wl - 0.5f;
      const float y = (ry + ay / (float)Hl) * (float)Hl - 0.5f;
      const float x0f = floorf(x), y0f = floorf(y);
      const float wx = x - x0f, wy = y - y0f;
      const int x0 = (int)x0f, y0 = (int)y0f;
      const float wp = e[l * 4 + p] * inv;
      #pragma unroll
      for (int dy = 0; dy < 2; ++dy) {
        #pragma unroll
        for (int dx = 0; dx < 2; ++dx) {
          const int xi = x0 + dx, yi = y0 + dy;
          if (xi >= 0 && xi < Wl && yi >= 0 && yi < Hl) {
            const float w = (dx ? wx : 1.f - wx) * (dy ? wy : 1.f - wy);
            const bf16* vrow = value + ((size_t)(b * (size_t)Ss + st + yi * Wl + xi) * Cc + h * 32);
            acc = fmaf(wp * w, __bfloat162float(vrow[d]), acc);
          }
        }
      }
    }
  }
  acc += __shfl_xor(acc, 32);
  if (lane < 32) accp[(size_t)(b * Qq + qi) * Cc + h * 32 + d] = acc;
}

// ---------------------------------------------------------------------------
extern "C" void kernel_launch(void* const* d_in, const int* in_sizes, int n_in,
                              void* d_out, int out_size, void* d_ws, size_t ws_size,
                              hipStream_t stream) {
  const float* tgt   = (const float*)d_in[0];
  const float* qpos  = (const float*)d_in[2];
  const float* refp  = (const float*)d_in[3];
  const float* src   = (const float*)d_in[4];
  const float* wq = (const float*)d_in[8];   const float* bq = (const float*)d_in[9];
  const float* wk = (const float*)d_in[10];  const float* bk = (const float*)d_in[11];
  const float* wv = (const float*)d_in[12];  const float* bv = (const float*)d_in[13];
  const float* wo = (const float*)d_in[14];  const float* bo = (const float*)d_in[15];
  const float* w_off = (const float*)d_in[16];  const float* b_off = (const float*)d_in[17];
  const float* w_attn = (const float*)d_in[18]; const float* b_attn = (const float*)d_in[19];
  const float* w_val = (const float*)d_in[20];  const float* b_val = (const float*)d_in[21];
  const float* w_out = (const float*)d_in[22];  const float* b_out = (const float*)d_in[23];
  const float* w1 = (const float*)d_in[24];  const float* b1 = (const float*)d_in[25];
  const float* w2 = (const float*)d_in[26];  const float* b2 = (const float*)d_in[27];
  const float* ln2g = (const float*)d_in[28]; const float* ln2b = (const float*)d_in[29];
  const float* ln1g = (const float*)d_in[30]; const float* ln1b = (const float*)d_in[31];
  const float* ln3g = (const float*)d_in[32]; const float* ln3b = (const float*)d_in[33];

  float* fws = (float*)d_ws;
  const size_t NBQ = (size_t)Bb * Qq * Cc;  // 614400
  float* qhb  = fws;
  float* khb  = qhb  + NBQ;
  float* vhb  = khb  + NBQ;
  float* sab  = vhb  + NBQ;
  float* sapb = sab  + NBQ;
  float* tgt1 = sapb + NBQ;
  float* offb = tgt1 + NBQ;
  float* accb = offb + NBQ;
  float* t2pb = accb + NBQ;
  float* t2nb = t2pb + NBQ;
  float* awlb = t2nb + NBQ;                       // 2400*128
  float* ffhb = awlb + (size_t)Bb * Qq * 128;     // 2400*1024
  float* ff2b = ffhb + (size_t)Bb * Qq * DFFf;    // NBQ
  bf16*  valb = (bf16*)(ff2b + NBQ);              // 174080*256 bf16
  __bf16* Bpk = (__bf16*)(valb + (size_t)Bb * Ss * Cc);  // 1984*512 bf16

  const int MQ = Bb * Qq;          // 2400
  const int MT = (MQ + 63) / 64;   // 38
  dim3 blk(256, 1, 1);

  pack_weights<<<dim3((FR_TOTAL + 3) / 4), blk, 0, stream>>>(
      wq, wk, wv, wo, w_val, w_off, w_attn, w_out, w1, w2, Bpk);

  gemm_qkv<<<dim3(6, MT), blk, 0, stream>>>(tgt, qpos, Bpk, bq, bk, bv, qhb, khb, vhb, MQ);
  attn3_kernel<<<dim3(Bb * NHh * 19), blk, 0, stream>>>(qhb, khb, vhb, sab);
  gemm64<8, false><<<dim3(2, MT), blk, 0, stream>>>(sab, nullptr, Bpk + (size_t)FR_WO * 512, bo, sapb, MQ, 256);
  ln_kernel<<<dim3(MQ), blk, 0, stream>>>(tgt, sapb, ln2g, ln2b, tgt1);

  // value projection (dominant GEMM) -> bf16
  value_gemm<<<dim3((Bb * Ss) / 128), dim3(512), 0, stream>>>(
      src, Bpk + (size_t)FR_WVAL * 512, b_val, valb);

  gemm_offattn<<<dim3(3, MT), blk, 0, stream>>>(tgt1, qpos, Bpk, b_off, b_attn, offb, awlb, MQ);

  deform_kernel<<<dim3(Bb * Qq * NHh / 4), blk, 0, stream>>>(offb, awlb, refp, valb, accb);

  gemm64<8, false><<<dim3(2, MT), blk, 0, stream>>>(accb, nullptr, Bpk + (size_t)FR_WOUT * 512, b_out, t2pb, MQ, 256);
  ln_kernel<<<dim3(MQ), blk, 0, stream>>>(tgt1, t2pb, ln1g, ln1b, t2nb);

  // FFN
  gemm64<8, true><<<dim3(8, MT), blk, 0, stream>>>(t2nb, nullptr, Bpk + (size_t)FR_W1 * 512, b1, ffhb, MQ, DFFf);
  gemm64<32, false><<<dim3(2, MT), blk, 0, stream>>>(ffhb, nullptr, Bpk + (size_t)FR_W2 * 512, b2, ff2b, MQ, 256);
  ln_kernel<<<dim3(MQ), blk, 0, stream>>>(t2nb, ff2b, ln3g, ln3b, (float*)d_out);
}

// Round 6
// 277.529 us; speedup vs baseline: 5.4096x; 1.0432x over previous
//
#include <hip/hip_runtime.h>
#include <hip/hip_bf16.h>
#include <math.h>

#define Bb   8
#define Qq   300
#define Cc   256
#define NHh  8
#define DHh  32
#define Ss   21760
#define DFFf 1024
#define LN_EPS 1e-5f

typedef __hip_bfloat16 bf16;
typedef unsigned short u16;
typedef unsigned int u32;
typedef __bf16 bf16x8_t __attribute__((ext_vector_type(8)));
typedef float f32x4_t __attribute__((ext_vector_type(4)));

__device__ inline u16 f2bf(float f) {
  union { float f; u32 u; } v; v.f = f;
  u32 u = v.u + 0x7fffu + ((v.u >> 16) & 1u);
  return (u16)(u >> 16);
}
__device__ inline float bfbits_lo(u32 w) {
  union { u32 u; float f; } v; v.u = w << 16;
  return v.f;
}
__device__ inline float bfbits_hi(u32 w) {
  union { u32 u; float f; } v; v.u = w & 0xffff0000u;
  return v.f;
}

// Packed-weight fragment bases (in 512-elem frag units).
// Layout per frag (gnf, kt): elem (lane, j) = W[gnf*16 + (lane&15)][kt*32 + (lane>>4)*8 + j]
#define FR_WQ    0
#define FR_WK    128
#define FR_WV    256
#define FR_WO    384
#define FR_WVAL  512
#define FR_WOFF  640
#define FR_WATTN 768
#define FR_WOUT  832
#define FR_W1    960
#define FR_W2    1472
#define FR_TOTAL 1984

// ---------------------------------------------------------------------------
// Pack all weights fp32 [N][K] -> bf16 MFMA B-fragment layout. 1 wave = 1 frag.
// ---------------------------------------------------------------------------
__global__ __launch_bounds__(256) void pack_weights(
    const float* __restrict__ wq, const float* __restrict__ wk,
    const float* __restrict__ wv, const float* __restrict__ wo,
    const float* __restrict__ wval, const float* __restrict__ woff,
    const float* __restrict__ wattn, const float* __restrict__ wout,
    const float* __restrict__ w1, const float* __restrict__ w2,
    __bf16* __restrict__ Bpk)
{
  const int gw = (int)((blockIdx.x * blockDim.x + threadIdx.x) >> 6);
  const int lane = threadIdx.x & 63;
  if (gw >= FR_TOTAL) return;
  const float* W; int KT, base;
  if      (gw < FR_WK)   { W = wq;    KT = 8;  base = FR_WQ; }
  else if (gw < FR_WV)   { W = wk;    KT = 8;  base = FR_WK; }
  else if (gw < FR_WO)   { W = wv;    KT = 8;  base = FR_WV; }
  else if (gw < FR_WVAL) { W = wo;    KT = 8;  base = FR_WO; }
  else if (gw < FR_WOFF) { W = wval;  KT = 8;  base = FR_WVAL; }
  else if (gw < FR_WATTN){ W = woff;  KT = 8;  base = FR_WOFF; }
  else if (gw < FR_WOUT) { W = wattn; KT = 8;  base = FR_WATTN; }
  else if (gw < FR_W1)   { W = wout;  KT = 8;  base = FR_WOUT; }
  else if (gw < FR_W2)   { W = w1;    KT = 8;  base = FR_W1; }
  else                   { W = w2;    KT = 32; base = FR_W2; }
  const int f = gw - base;
  const int nf = f / KT, kt = f % KT;
  const int col = nf * 16 + (lane & 15);
  const int k0 = kt * 32 + (lane >> 4) * 8;
  const int K = KT * 32;
  const float4 a = *reinterpret_cast<const float4*>(W + (size_t)col * K + k0);
  const float4 b = *reinterpret_cast<const float4*>(W + (size_t)col * K + k0 + 4);
  bf16x8_t p = { (__bf16)a.x, (__bf16)a.y, (__bf16)a.z, (__bf16)a.w,
                 (__bf16)b.x, (__bf16)b.y, (__bf16)b.z, (__bf16)b.w };
  *reinterpret_cast<bf16x8_t*>(Bpk + ((size_t)gw * 64 + lane) * 8) = p;
}

// ---------------------------------------------------------------------------
// Small-GEMM body: BM=64, BN=128, 256 threads (4 waves, wave tile 32x64).
// A fp32 staged->bf16 in LDS; B direct from packed-fragment global (L2-hot).
// ---------------------------------------------------------------------------
template<int KT, bool RELU>
__device__ __forceinline__ void gemm64_body(
    __bf16 (*As)[40],
    const float* __restrict__ A, const float* __restrict__ A2,
    const __bf16* __restrict__ Wp, const float* __restrict__ bias,
    float* __restrict__ out, int M, int N, int m0, int n0)
{
  const int tid = threadIdx.x;
  const int w = tid >> 6, lane = tid & 63;
  const int wm = w >> 1, wn = w & 1;
  const int fr = lane & 15, fq = lane >> 4;
  const int sr = tid >> 2, sk = (tid & 3) * 8;
  constexpr int K = KT * 32;

  const int arow = (m0 + sr < M) ? (m0 + sr) : (M - 1);
  const float* aptr = A + (size_t)arow * K;
  const float* a2ptr = A2 ? (A2 + (size_t)arow * K) : nullptr;
  const __bf16* wp = Wp + (size_t)((n0 >> 4) + wn * 4) * KT * 512 + (size_t)lane * 8;

  f32x4_t acc[2][4];
  const f32x4_t zz = {0.f, 0.f, 0.f, 0.f};
  #pragma unroll
  for (int m = 0; m < 2; ++m)
    #pragma unroll
    for (int n = 0; n < 4; ++n) acc[m][n] = zz;

  for (int kt = 0; kt < KT; ++kt) {
    const int kg = kt * 32 + sk;
    float4 a0 = *reinterpret_cast<const float4*>(aptr + kg);
    float4 a1 = *reinterpret_cast<const float4*>(aptr + kg + 4);
    if (a2ptr) {
      const float4 c0 = *reinterpret_cast<const float4*>(a2ptr + kg);
      const float4 c1 = *reinterpret_cast<const float4*>(a2ptr + kg + 4);
      a0.x += c0.x; a0.y += c0.y; a0.z += c0.z; a0.w += c0.w;
      a1.x += c1.x; a1.y += c1.y; a1.z += c1.z; a1.w += c1.w;
    }
    const bf16x8_t pa = { (__bf16)a0.x, (__bf16)a0.y, (__bf16)a0.z, (__bf16)a0.w,
                          (__bf16)a1.x, (__bf16)a1.y, (__bf16)a1.z, (__bf16)a1.w };
    bf16x8_t bfr[4];
    #pragma unroll
    for (int n = 0; n < 4; ++n)
      bfr[n] = *reinterpret_cast<const bf16x8_t*>(wp + (size_t)(n * KT + kt) * 512);
    __syncthreads();    // previous iteration's LDS reads complete
    *reinterpret_cast<bf16x8_t*>(&As[sr][sk]) = pa;
    __syncthreads();
    bf16x8_t af[2];
    #pragma unroll
    for (int m = 0; m < 2; ++m)
      af[m] = *reinterpret_cast<const bf16x8_t*>(&As[wm*32 + m*16 + fr][fq*8]);
    #pragma unroll
    for (int m = 0; m < 2; ++m)
      #pragma unroll
      for (int n = 0; n < 4; ++n)
        acc[m][n] = __builtin_amdgcn_mfma_f32_16x16x32_bf16(af[m], bfr[n], acc[m][n], 0, 0, 0);
  }

  #pragma unroll
  for (int m = 0; m < 2; ++m) {
    const int row = m0 + wm*32 + m*16 + fq*4;
    #pragma unroll
    for (int n = 0; n < 4; ++n) {
      const int col = n0 + wn*64 + n*16 + fr;
      const float bc = bias[col];
      #pragma unroll
      for (int j = 0; j < 4; ++j) {
        if (row + j < M) {
          float v = acc[m][n][j] + bc;
          if (RELU) v = fmaxf(v, 0.f);
          out[(size_t)(row + j) * N + col] = v;
        }
      }
    }
  }
}

template<int KT, bool RELU>
__global__ __launch_bounds__(256) void gemm64(
    const float* __restrict__ A, const float* __restrict__ A2,
    const __bf16* __restrict__ Wp, const float* __restrict__ bias,
    float* __restrict__ out, int M, int N)
{
  __shared__ __bf16 As[64][40];
  gemm64_body<KT, RELU>(As, A, A2, Wp, bias, out, M, N, blockIdx.y * 64, blockIdx.x * 128);
}

// Fused q/k/v projections: blockIdx.x 0..5 -> (sel = x>>1, n0 = (x&1)*128)
__global__ __launch_bounds__(256) void gemm_qkv(
    const float* __restrict__ tgt, const float* __restrict__ qpos,
    const __bf16* __restrict__ Bpk,
    const float* __restrict__ bq, const float* __restrict__ bk, const float* __restrict__ bv,
    float* __restrict__ qhb, float* __restrict__ khb, float* __restrict__ vhb, int M)
{
  __shared__ __bf16 As[64][40];
  const int sel = blockIdx.x >> 1;
  const int n0 = (blockIdx.x & 1) * 128;
  const __bf16* Wp; const float* bias; float* out; const float* A2;
  if (sel == 0)      { Wp = Bpk + (size_t)FR_WQ * 512; bias = bq; out = qhb; A2 = qpos; }
  else if (sel == 1) { Wp = Bpk + (size_t)FR_WK * 512; bias = bk; out = khb; A2 = qpos; }
  else               { Wp = Bpk + (size_t)FR_WV * 512; bias = bv; out = vhb; A2 = nullptr; }
  gemm64_body<8, false>(As, tgt, A2, Wp, bias, out, M, 256, blockIdx.y * 64, n0);
}

// Fused offset + attention-logit projections: blockIdx.x 0,1 -> w_off; 2 -> w_attn
__global__ __launch_bounds__(256) void gemm_offattn(
    const float* __restrict__ tgt1, const float* __restrict__ qpos,
    const __bf16* __restrict__ Bpk,
    const float* __restrict__ b_off, const float* __restrict__ b_attn,
    float* __restrict__ offb, float* __restrict__ awlb, int M)
{
  __shared__ __bf16 As[64][40];
  const int bx = blockIdx.x;
  if (bx < 2)
    gemm64_body<8, false>(As, tgt1, qpos, Bpk + (size_t)FR_WOFF * 512, b_off, offb,
                          M, 256, blockIdx.y * 64, bx * 128);
  else
    gemm64_body<8, false>(As, tgt1, qpos, Bpk + (size_t)FR_WATTN * 512, b_attn, awlb,
                          M, 128, blockIdx.y * 64, 0);
}

// ---------------------------------------------------------------------------
// Value projection v2: 256 thr, 128x128 tile, async double-buffered A staging
// via global_load_lds (fp32, XOR-swizzled source <-> swizzled ds_read),
// B-fragments reg-prefetched one K-iter ahead. One barrier per K-iter.
// M = 174080 (multiple of 128).
// ---------------------------------------------------------------------------
__device__ __forceinline__ void stage_rowsA(
    const float* __restrict__ A, size_t m0, int kt,
    float* lds, int w, int lane)
{
  const int rr = lane >> 3;                 // row-within-8 = (r & 7)
  const int cc = (lane & 7) ^ rr;           // inverse-swizzled source chunk
  #pragma unroll
  for (int j = 0; j < 4; ++j) {
    const int r = w * 32 + j * 8 + rr;
    const float* g = A + (size_t)(m0 + r) * 256 + kt * 32 + cc * 4;
    __builtin_amdgcn_global_load_lds(
        (const __attribute__((address_space(1))) void*)g,
        (__attribute__((address_space(3))) void*)(lds + w * 1024 + j * 256),
        16, 0, 0);
  }
}

__global__ __launch_bounds__(256) void value_gemm(
    const float* __restrict__ A, const __bf16* __restrict__ Wp,
    const float* __restrict__ bias, bf16* __restrict__ out)
{
  __shared__ float Asb[2][4096];            // 2 x 128 rows x 32 f32 (16 KB each)
  const int tid = threadIdx.x;
  const int w = tid >> 6, lane = tid & 63;
  const int wm = w >> 1, wn = w & 1;
  const int fr = lane & 15, fq = lane >> 4;
  const size_t m0 = (size_t)blockIdx.x * 128;
  const int n0 = blockIdx.y * 128;

  const __bf16* wp = Wp + (size_t)(((n0 >> 4) + wn * 4) * 8) * 512 + (size_t)lane * 8;

  f32x4_t acc[4][4];
  const f32x4_t zz = {0.f, 0.f, 0.f, 0.f};
  #pragma unroll
  for (int m = 0; m < 4; ++m)
    #pragma unroll
    for (int n = 0; n < 4; ++n) acc[m][n] = zz;

  // prologue: stage kt=0, prefetch B(kt=0)
  stage_rowsA(A, m0, 0, Asb[0], w, lane);
  bf16x8_t bcur[4], bnext[4];
  #pragma unroll
  for (int n = 0; n < 4; ++n)
    bcur[n] = *reinterpret_cast<const bf16x8_t*>(wp + (size_t)(n * 8) * 512);

  for (int kt = 0; kt < 8; ++kt) {
    __syncthreads();                        // drains stage(kt) + B(kt); barrier
    if (kt < 7) {
      stage_rowsA(A, m0, kt + 1, Asb[(kt + 1) & 1], w, lane);
      #pragma unroll
      for (int n = 0; n < 4; ++n)
        bnext[n] = *reinterpret_cast<const bf16x8_t*>(wp + (size_t)(n * 8 + kt + 1) * 512);
    }
    const float* Ab = Asb[kt & 1];
    bf16x8_t af[4];
    #pragma unroll
    for (int m = 0; m < 4; ++m) {
      const int r = wm * 64 + m * 16 + fr;
      const int sw = fr & 7;
      const f32x4_t v0 = *reinterpret_cast<const f32x4_t*>(Ab + r * 32 + (((fq * 2)     ^ sw) << 2));
      const f32x4_t v1 = *reinterpret_cast<const f32x4_t*>(Ab + r * 32 + (((fq * 2 + 1) ^ sw) << 2));
      af[m] = bf16x8_t{ (__bf16)v0[0], (__bf16)v0[1], (__bf16)v0[2], (__bf16)v0[3],
                        (__bf16)v1[0], (__bf16)v1[1], (__bf16)v1[2], (__bf16)v1[3] };
    }
    #pragma unroll
    for (int m = 0; m < 4; ++m)
      #pragma unroll
      for (int n = 0; n < 4; ++n)
        acc[m][n] = __builtin_amdgcn_mfma_f32_16x16x32_bf16(af[m], bcur[n], acc[m][n], 0, 0, 0);
    if (kt < 7) {
      #pragma unroll
      for (int n = 0; n < 4; ++n) bcur[n] = bnext[n];
    }
  }

  #pragma unroll
  for (int m = 0; m < 4; ++m) {
    const size_t row = m0 + wm * 64 + m * 16 + fq * 4;
    #pragma unroll
    for (int n = 0; n < 4; ++n) {
      const int col = n0 + wn * 64 + n * 16 + fr;
      const float bc = bias[col];
      #pragma unroll
      for (int j = 0; j < 4; ++j)
        out[(row + j) * 256 + col] = __float2bfloat16(acc[m][n][j] + bc);
    }
  }
}

// ---------------------------------------------------------------------------
// Self-attention: wave-per-q-row. Block = (b, h, 16-row q-tile), 4 waves.
// ---------------------------------------------------------------------------
__global__ __launch_bounds__(256) void attn3_kernel(
    const float* __restrict__ qh, const float* __restrict__ kh,
    const float* __restrict__ vh, float* __restrict__ sa)
{
  __shared__ float Kf[300][34];
  __shared__ u16  Vb[304][36];
  __shared__ float pbuf[4][304];
  const int blk = blockIdx.x;
  const int qt = blk % 19;
  const int bh = blk / 19;
  const int h = bh & 7, b = bh >> 3;
  const int tid = threadIdx.x;
  const size_t base = ((size_t)b * Qq) * Cc + h * DHh;

  for (int idx = tid; idx < Qq * DHh; idx += 256) {
    const int k = idx >> 5, d = idx & 31;
    Kf[k][d] = kh[base + (size_t)k * Cc + d] * 0.17677669529663687f;
  }
  for (int idx = tid; idx < 304 * DHh; idx += 256) {
    const int k = idx >> 5, d = idx & 31;
    Vb[k][d] = (k < Qq) ? f2bf(vh[base + (size_t)k * Cc + d]) : (u16)0;
  }
  __syncthreads();

  const int wv = tid >> 6, lane = tid & 63;
  const int qtr = lane >> 4, dp = lane & 15;

  for (int r = 0; r < 4; ++r) {
    const int q0 = qt * 16 + wv * 4 + r;
    const int q = (q0 < Qq) ? q0 : (Qq - 1);
    const float* qp = qh + base + (size_t)q * Cc;
    float qv[32];
    #pragma unroll
    for (int i = 0; i < 8; ++i) {
      const float4 t = reinterpret_cast<const float4*>(qp)[i];
      qv[i*4+0] = t.x; qv[i*4+1] = t.y; qv[i*4+2] = t.z; qv[i*4+3] = t.w;
    }

    float e[5];
    float mx = -1e30f;
    #pragma unroll
    for (int i = 0; i < 5; ++i) {
      const int k = lane + i * 64;
      if (k < Qq) {
        const float2* kp = reinterpret_cast<const float2*>(Kf[k]);
        float s = 0.f;
        #pragma unroll
        for (int d2 = 0; d2 < 16; ++d2) {
          const float2 kvp = kp[d2];
          s = fmaf(qv[2*d2], kvp.x, s);
          s = fmaf(qv[2*d2+1], kvp.y, s);
        }
        e[i] = s;
      } else {
        e[i] = -1e30f;
      }
      mx = fmaxf(mx, e[i]);
    }
    #pragma unroll
    for (int o = 32; o; o >>= 1) mx = fmaxf(mx, __shfl_xor(mx, o));
    float ssum = 0.f;
    #pragma unroll
    for (int i = 0; i < 5; ++i) { e[i] = __expf(e[i] - mx); ssum += e[i]; }
    #pragma unroll
    for (int o = 32; o; o >>= 1) ssum += __shfl_xor(ssum, o);
    const float inv = 1.f / ssum;
    #pragma unroll
    for (int i = 0; i < 5; ++i) {
      const int k = lane + i * 64;
      if (k < 304) pbuf[wv][k] = (k < Qq) ? e[i] * inv : 0.f;
    }
    __syncthreads();

    float accA = 0.f, accB = 0.f;
    const float* prow = pbuf[wv] + qtr * 76;
    #pragma unroll 4
    for (int j4 = 0; j4 < 19; ++j4) {
      const float4 pv4 = *reinterpret_cast<const float4*>(prow + j4 * 4);
      const int kb = qtr * 76 + j4 * 4;
      const u32 v0 = *reinterpret_cast<const u32*>(&Vb[kb + 0][2*dp]);
      const u32 v1 = *reinterpret_cast<const u32*>(&Vb[kb + 1][2*dp]);
      const u32 v2 = *reinterpret_cast<const u32*>(&Vb[kb + 2][2*dp]);
      const u32 v3 = *reinterpret_cast<const u32*>(&Vb[kb + 3][2*dp]);
      accA = fmaf(pv4.x, bfbits_lo(v0), accA); accB = fmaf(pv4.x, bfbits_hi(v0), accB);
      accA = fmaf(pv4.y, bfbits_lo(v1), accA); accB = fmaf(pv4.y, bfbits_hi(v1), accB);
      accA = fmaf(pv4.z, bfbits_lo(v2), accA); accB = fmaf(pv4.z, bfbits_hi(v2), accB);
      accA = fmaf(pv4.w, bfbits_lo(v3), accA); accB = fmaf(pv4.w, bfbits_hi(v3), accB);
    }
    accA += __shfl_xor(accA, 16); accA += __shfl_xor(accA, 32);
    accB += __shfl_xor(accB, 16); accB += __shfl_xor(accB, 32);
    if (q0 < Qq && lane < 16) {
      float2 st; st.x = accA; st.y = accB;
      *reinterpret_cast<float2*>(sa + base + (size_t)q * Cc + 2 * dp) = st;
    }
    __syncthreads();
  }
}

// ---------------------------------------------------------------------------
// Fused residual-add + LayerNorm over C=256. One block (256 thr) per row.
// ---------------------------------------------------------------------------
__global__ __launch_bounds__(256) void ln_kernel(
    const float* __restrict__ x, const float* __restrict__ y,
    const float* __restrict__ g, const float* __restrict__ bta,
    float* __restrict__ out)
{
  const int row = blockIdx.x;
  const int t = threadIdx.x;
  const size_t idx = (size_t)row * Cc + t;
  const float v = x[idx] + y[idx];
  float s = v;
  #pragma unroll
  for (int o = 32; o; o >>= 1) s += __shfl_xor(s, o);
  __shared__ float ps[4], qs[4];
  const int wid = t >> 6, lane = t & 63;
  if (lane == 0) ps[wid] = s;
  __syncthreads();
  const float mean = (ps[0] + ps[1] + ps[2] + ps[3]) * (1.f / Cc);
  const float dv = v - mean;
  float s2 = dv * dv;
  #pragma unroll
  for (int o = 32; o; o >>= 1) s2 += __shfl_xor(s2, o);
  if (lane == 0) qs[wid] = s2;
  __syncthreads();
  const float var = (qs[0] + qs[1] + qs[2] + qs[3]) * (1.f / Cc);
  out[idx] = dv * rsqrtf(var + LN_EPS) * g[t] + bta[t];
}

// ---------------------------------------------------------------------------
// Deformable sampling v2: one wave per (b,q,h). lane = pt*16 + dp:
// pt in 0..3 = sampling point, dp in 0..15 = channel pair (u32 bf16x2 loads).
// Cross-point reduce via shfl_xor(16,32); lanes 0..15 write float2.
// ---------------------------------------------------------------------------
__global__ __launch_bounds__(256) void deform_kernel(
    const float* __restrict__ offb, const float* __restrict__ awl,
    const float* __restrict__ refp, const bf16* __restrict__ value,
    float* __restrict__ accp)
{
  const int gw = (int)((blockIdx.x * (size_t)blockDim.x + threadIdx.x) >> 6);
  if (gw >= Bb * Qq * NHh) return;
  const int lane = threadIdx.x & 63;
  const int h = gw % NHh;
  const int t = gw / NHh;
  const int qi = t % Qq;
  const int b = t / Qq;
  const int pt = lane >> 4;
  const int dp = lane & 15;

  const float* awp = awl + (size_t)(b * Qq + qi) * 128 + h * 16;
  float e[16];
  float mx = -1e30f;
  #pragma unroll
  for (int i = 0; i < 16; ++i) { e[i] = awp[i]; mx = fmaxf(mx, e[i]); }
  float s = 0.f;
  #pragma unroll
  for (int i = 0; i < 16; ++i) { e[i] = __expf(e[i] - mx); s += e[i]; }
  const float inv = 1.f / s;

  const float* offp = offb + (size_t)(b * Qq + qi) * Cc + h * 32;
  const float* rp = refp + (size_t)(b * Qq + qi) * 8;
  const int lH[4] = {128, 64, 32, 16};
  const int lW[4] = {128, 64, 32, 16};
  const int lS[4] = {0, 16384, 20480, 21504};

  const u16* vbase = reinterpret_cast<const u16*>(value) + (size_t)h * 32 + 2 * dp;

  float accx = 0.f, accy = 0.f;
  #pragma unroll
  for (int l = 0; l < 4; ++l) {
    const int Hl = lH[l], Wl = lW[l], st = lS[l];
    const float rx = rp[l * 2 + 0], ry = rp[l * 2 + 1];
    const float ax = offp[l * 8 + pt * 2 + 0];
    const float ay = offp[l * 8 + pt * 2 + 1];
    const float x = (rx + ax / (float)Wl) * (float)Wl - 0.5f;
    const float y = (ry + ay / (float)Hl) * (float)Hl - 0.5f;
    const float x0f = floorf(x), y0f = floorf(y);
    const float wx = x - x0f, wy = y - y0f;
    const int x0 = (int)x0f, y0 = (int)y0f;
    const float wp = e[l * 4 + pt] * inv;
    #pragma unroll
    for (int dy = 0; dy < 2; ++dy) {
      #pragma unroll
      for (int dx = 0; dx < 2; ++dx) {
        const int xi = x0 + dx, yi = y0 + dy;
        if (xi >= 0 && xi < Wl && yi >= 0 && yi < Hl) {
          const float wgt = wp * (dx ? wx : 1.f - wx) * (dy ? wy : 1.f - wy);
          const u32 v = *reinterpret_cast<const u32*>(
              vbase + (size_t)(b * (size_t)Ss + st + yi * Wl + xi) * Cc);
          accx = fmaf(wgt, bfbits_lo(v), accx);
          accy = fmaf(wgt, bfbits_hi(v), accy);
        }
      }
    }
  }
  accx += __shfl_xor(accx, 16); accx += __shfl_xor(accx, 32);
  accy += __shfl_xor(accy, 16); accy += __shfl_xor(accy, 32);
  if (lane < 16) {
    float2 st2; st2.x = accx; st2.y = accy;
    *reinterpret_cast<float2*>(accp + (size_t)(b * Qq + qi) * Cc + h * 32 + 2 * dp) = st2;
  }
}

// ---------------------------------------------------------------------------
extern "C" void kernel_launch(void* const* d_in, const int* in_sizes, int n_in,
                              void* d_out, int out_size, void* d_ws, size_t ws_size,
                              hipStream_t stream) {
  const float* tgt   = (const float*)d_in[0];
  const float* qpos  = (const float*)d_in[2];
  const float* refp  = (const float*)d_in[3];
  const float* src   = (const float*)d_in[4];
  const float* wq = (const float*)d_in[8];   const float* bq = (const float*)d_in[9];
  const float* wk = (const float*)d_in[10];  const float* bk = (const float*)d_in[11];
  const float* wv = (const float*)d_in[12];  const float* bv = (const float*)d_in[13];
  const float* wo = (const float*)d_in[14];  const float* bo = (const float*)d_in[15];
  const float* w_off = (const float*)d_in[16];  const float* b_off = (const float*)d_in[17];
  const float* w_attn = (const float*)d_in[18]; const float* b_attn = (const float*)d_in[19];
  const float* w_val = (const float*)d_in[20];  const float* b_val = (const float*)d_in[21];
  const float* w_out = (const float*)d_in[22];  const float* b_out = (const float*)d_in[23];
  const float* w1 = (const float*)d_in[24];  const float* b1 = (const float*)d_in[25];
  const float* w2 = (const float*)d_in[26];  const float* b2 = (const float*)d_in[27];
  const float* ln2g = (const float*)d_in[28]; const float* ln2b = (const float*)d_in[29];
  const float* ln1g = (const float*)d_in[30]; const float* ln1b = (const float*)d_in[31];
  const float* ln3g = (const float*)d_in[32]; const float* ln3b = (const float*)d_in[33];

  float* fws = (float*)d_ws;
  const size_t NBQ = (size_t)Bb * Qq * Cc;  // 614400
  float* qhb  = fws;
  float* khb  = qhb  + NBQ;
  float* vhb  = khb  + NBQ;
  float* sab  = vhb  + NBQ;
  float* sapb = sab  + NBQ;
  float* tgt1 = sapb + NBQ;
  float* offb = tgt1 + NBQ;
  float* accb = offb + NBQ;
  float* t2pb = accb + NBQ;
  float* t2nb = t2pb + NBQ;
  float* awlb = t2nb + NBQ;                       // 2400*128
  float* ffhb = awlb + (size_t)Bb * Qq * 128;     // 2400*1024
  float* ff2b = ffhb + (size_t)Bb * Qq * DFFf;    // NBQ
  bf16*  valb = (bf16*)(ff2b + NBQ);              // 174080*256 bf16
  __bf16* Bpk = (__bf16*)(valb + (size_t)Bb * Ss * Cc);  // 1984*512 bf16

  const int MQ = Bb * Qq;          // 2400
  const int MT = (MQ + 63) / 64;   // 38
  dim3 blk(256, 1, 1);

  pack_weights<<<dim3((FR_TOTAL + 3) / 4), blk, 0, stream>>>(
      wq, wk, wv, wo, w_val, w_off, w_attn, w_out, w1, w2, Bpk);

  gemm_qkv<<<dim3(6, MT), blk, 0, stream>>>(tgt, qpos, Bpk, bq, bk, bv, qhb, khb, vhb, MQ);
  attn3_kernel<<<dim3(Bb * NHh * 19), blk, 0, stream>>>(qhb, khb, vhb, sab);
  gemm64<8, false><<<dim3(2, MT), blk, 0, stream>>>(sab, nullptr, Bpk + (size_t)FR_WO * 512, bo, sapb, MQ, 256);
  ln_kernel<<<dim3(MQ), blk, 0, stream>>>(tgt, sapb, ln2g, ln2b, tgt1);

  // value projection (dominant GEMM) -> bf16, async-pipelined
  value_gemm<<<dim3((Bb * Ss) / 128, 2), blk, 0, stream>>>(
      src, Bpk + (size_t)FR_WVAL * 512, b_val, valb);

  gemm_offattn<<<dim3(3, MT), blk, 0, stream>>>(tgt1, qpos, Bpk, b_off, b_attn, offb, awlb, MQ);

  deform_kernel<<<dim3(Bb * Qq * NHh / 4), blk, 0, stream>>>(offb, awlb, refp, valb, accb);

  gemm64<8, false><<<dim3(2, MT), blk, 0, stream>>>(accb, nullptr, Bpk + (size_t)FR_WOUT * 512, b_out, t2pb, MQ, 256);
  ln_kernel<<<dim3(MQ), blk, 0, stream>>>(tgt1, t2pb, ln1g, ln1b, t2nb);

  // FFN
  gemm64<8, true><<<dim3(8, MT), blk, 0, stream>>>(t2nb, nullptr, Bpk + (size_t)FR_W1 * 512, b1, ffhb, MQ, DFFf);
  gemm64<32, false><<<dim3(2, MT), blk, 0, stream>>>(ffhb, nullptr, Bpk + (size_t)FR_W2 * 512, b2, ff2b, MQ, 256);
  ln_kernel<<<dim3(MQ), blk, 0, stream>>>(t2nb, ff2b, ln3g, ln3b, (float*)d_out);
}